// Round 1
// baseline (1839.989 us; speedup 1.0000x reference)
//
#include <hip/hip_runtime.h>

#define T91  91
#define FDIM 256
#define HNUM 4
#define DDIM 64
#define ANUM 128
#define RNUM 1024
#define KFDIM 1024

// ---------------------------------------------------------------------------
// Generic 64x64 tiled fp32 GEMM:  out = epilogue(A[N,K] @ B[K,M] + bias)
// MODE 0: K/V proj  -> relu, store permuted [T,H,RNUM,D]
// MODE 1: Q proj    -> relu * q_scale[d], store permuted [T,H,ANUM,D]
// MODE 3: Y2        -> relu + agent (aux), store row-major [N,M]
// MODE 4: F1        -> relu, store row-major [N,M]
// ---------------------------------------------------------------------------
template<int MODE>
__global__ __launch_bounds__(256) void gemm64(
    const float* __restrict__ A, const float* __restrict__ B,
    const float* __restrict__ bias, float* __restrict__ out,
    int N, int M, int K, const float* __restrict__ aux) {
  __shared__ float As[16][68];   // [k][row], padded: 272B row stride (16B-aligned)
  __shared__ float Bs[16][64];   // [k][col]

  const int tid = threadIdx.x;
  const int tx = tid & 15;       // col group: cols tx*4 .. tx*4+3
  const int ty = tid >> 4;       // row group: rows ty*4 .. ty*4+3
  const int n0 = blockIdx.y * 64;
  const int m0 = blockIdx.x * 64;

  const int arow = tid >> 2;          // 0..63
  const int ak   = (tid & 3) * 4;     // 0,4,8,12
  const int bk   = tid >> 4;          // 0..15
  const int bcol = (tid & 15) * 4;    // 0..60

  float acc[4][4];
  #pragma unroll
  for (int j = 0; j < 4; ++j)
    #pragma unroll
    for (int i = 0; i < 4; ++i) acc[j][i] = 0.f;

  for (int k0 = 0; k0 < K; k0 += 16) {
    float4 av = *(const float4*)&A[(size_t)(n0 + arow) * K + k0 + ak];
    float4 bv = *(const float4*)&B[(size_t)(k0 + bk) * M + m0 + bcol];
    __syncthreads();
    As[ak + 0][arow] = av.x;
    As[ak + 1][arow] = av.y;
    As[ak + 2][arow] = av.z;
    As[ak + 3][arow] = av.w;
    *(float4*)&Bs[bk][bcol] = bv;
    __syncthreads();
    #pragma unroll
    for (int k = 0; k < 16; ++k) {
      float4 a4 = *(const float4*)&As[k][ty * 4];
      float4 b4 = *(const float4*)&Bs[k][tx * 4];
      float aj[4] = {a4.x, a4.y, a4.z, a4.w};
      float bi[4] = {b4.x, b4.y, b4.z, b4.w};
      #pragma unroll
      for (int j = 0; j < 4; ++j)
        #pragma unroll
        for (int i = 0; i < 4; ++i)
          acc[j][i] += aj[j] * bi[i];
    }
  }

  const int c0 = m0 + tx * 4;
  #pragma unroll
  for (int j = 0; j < 4; ++j) {
    const int n = n0 + ty * 4 + j;
    float v[4];
    #pragma unroll
    for (int i = 0; i < 4; ++i)
      v[i] = fmaxf(acc[j][i] + bias[c0 + i], 0.f);

    if (MODE == 0) {                 // K/V: n = r*T + t ; col = h*64 + d
      const int rr = n / T91, tt = n - rr * T91;
      const int h = c0 >> 6, d0 = c0 & 63;
      float4 o = {v[0], v[1], v[2], v[3]};
      *(float4*)&out[(((size_t)tt * HNUM + h) * RNUM + rr) * DDIM + d0] = o;
    } else if (MODE == 1) {          // Q: n = a*T + t ; scale by q_scale[d]
      const int ai = n / T91, tt = n - ai * T91;
      const int h = c0 >> 6, d0 = c0 & 63;
      float4 o = {v[0] * aux[d0 + 0], v[1] * aux[d0 + 1],
                  v[2] * aux[d0 + 2], v[3] * aux[d0 + 3]};
      *(float4*)&out[(((size_t)tt * HNUM + h) * ANUM + ai) * DDIM + d0] = o;
    } else if (MODE == 3) {          // Y2 + agent residual -> S
      float4 ag = *(const float4*)&aux[(size_t)n * FDIM + c0];
      float4 o = {v[0] + ag.x, v[1] + ag.y, v[2] + ag.z, v[3] + ag.w};
      *(float4*)&out[(size_t)n * FDIM + c0] = o;
    } else {                         // F1 plain relu
      float4 o = {v[0], v[1], v[2], v[3]};
      *(float4*)&out[(size_t)n * M + c0] = o;
    }
  }
}

// ---------------------------------------------------------------------------
// Flash-style attention per (t,h): Q[128,64] x K[1024,64] -> softmax -> V
// 128 threads, 1 query row per thread, online softmax over R chunks of 32.
// Writes Y1 in [A, T, F] layout (a*T + t row, h*64+d col).
// ---------------------------------------------------------------------------
__global__ __launch_bounds__(128) void attn_kernel(
    const float* __restrict__ Qh, const float* __restrict__ Kh,
    const float* __restrict__ Vh, float* __restrict__ Y1) {
  const int th = blockIdx.x;          // t*4 + h
  const int t = th >> 2, h = th & 3;
  const int a = threadIdx.x;          // 0..127

  __shared__ float Kl[32][64];
  __shared__ float Vl[32][64];

  float q[64], acc[64];
  const float* qp = Qh + ((size_t)th * ANUM + a) * DDIM;
  #pragma unroll
  for (int i = 0; i < 16; ++i) {
    float4 v = *(const float4*)&qp[i * 4];
    q[4 * i + 0] = v.x; q[4 * i + 1] = v.y; q[4 * i + 2] = v.z; q[4 * i + 3] = v.w;
  }
  #pragma unroll
  for (int d = 0; d < 64; ++d) acc[d] = 0.f;

  float m = -1e30f, l = 0.f;
  const float* Kb = Kh + (size_t)th * RNUM * DDIM;
  const float* Vb = Vh + (size_t)th * RNUM * DDIM;

  const int lr = a >> 2;              // 0..31
  const int lc = (a & 3) * 16;        // 0,16,32,48

  for (int r0 = 0; r0 < RNUM; r0 += 32) {
    __syncthreads();
    #pragma unroll
    for (int qq = 0; qq < 4; ++qq) {
      *(float4*)&Kl[lr][lc + qq * 4] =
          *(const float4*)&Kb[(size_t)(r0 + lr) * DDIM + lc + qq * 4];
      *(float4*)&Vl[lr][lc + qq * 4] =
          *(const float4*)&Vb[(size_t)(r0 + lr) * DDIM + lc + qq * 4];
    }
    __syncthreads();

    float e[32];
    float em = -1e30f;
    #pragma unroll
    for (int r = 0; r < 32; ++r) {
      const float4* kp = (const float4*)&Kl[r][0];
      float s = 0.f;
      #pragma unroll
      for (int i = 0; i < 16; ++i) {
        float4 kv = kp[i];
        s += q[4 * i + 0] * kv.x + q[4 * i + 1] * kv.y
           + q[4 * i + 2] * kv.z + q[4 * i + 3] * kv.w;
      }
      e[r] = s * 0.5f;                // / sqrt(H) = / 2
      em = fmaxf(em, e[r]);
    }
    const float mn = fmaxf(m, em);
    const float f = __expf(m - mn);
    l *= f;
    #pragma unroll
    for (int d = 0; d < 64; ++d) acc[d] *= f;
    #pragma unroll
    for (int r = 0; r < 32; ++r) {
      const float p = __expf(e[r] - mn);
      l += p;
      const float4* vp = (const float4*)&Vl[r][0];
      #pragma unroll
      for (int i = 0; i < 16; ++i) {
        float4 vv = vp[i];
        acc[4 * i + 0] += p * vv.x; acc[4 * i + 1] += p * vv.y;
        acc[4 * i + 2] += p * vv.z; acc[4 * i + 3] += p * vv.w;
      }
    }
    m = mn;
  }

  const float inv = 1.f / l;
  float* yp = Y1 + ((size_t)a * T91 + t) * FDIM + h * DDIM;
  #pragma unroll
  for (int i = 0; i < 16; ++i) {
    float4 o = {acc[4 * i + 0] * inv, acc[4 * i + 1] * inv,
                acc[4 * i + 2] * inv, acc[4 * i + 3] * inv};
    *(float4*)&yp[i * 4] = o;
  }
}

// ---------------------------------------------------------------------------
// F2 = relu(F1 @ W_F2 + b), then LayerNorm -> Z.  BM=32, BN=256 (full row).
// 256 threads: ty=tid/32 (4 rows each), tx=tid%32 (cols tx*4+{0..3}, +128).
// ---------------------------------------------------------------------------
__global__ __launch_bounds__(256) void f2_ln_kernel(
    const float* __restrict__ F1b, const float* __restrict__ W2,
    const float* __restrict__ b2, const float* __restrict__ g,
    const float* __restrict__ bb, float* __restrict__ Z) {
  __shared__ float As[16][36];    // [k][row], 144B stride (16B-aligned)
  __shared__ float Bs[16][256];   // [k][col]

  const int tid = threadIdx.x;
  const int tx = tid & 31;
  const int ty = tid >> 5;        // 0..7
  const int n0 = blockIdx.x * 32;

  const int arow = tid >> 3;          // 0..31
  const int ak   = (tid & 7) * 2;     // 0..14
  const int bk   = tid >> 4;          // 0..15
  const int bc   = (tid & 15) * 16;   // 0..240

  float acc[4][8];
  #pragma unroll
  for (int j = 0; j < 4; ++j)
    #pragma unroll
    for (int i = 0; i < 8; ++i) acc[j][i] = 0.f;

  for (int k0 = 0; k0 < KFDIM; k0 += 16) {
    float2 av = *(const float2*)&F1b[(size_t)(n0 + arow) * KFDIM + k0 + ak];
    float4 bv[4];
    #pragma unroll
    for (int qq = 0; qq < 4; ++qq)
      bv[qq] = *(const float4*)&W2[(size_t)(k0 + bk) * FDIM + bc + qq * 4];
    __syncthreads();
    As[ak + 0][arow] = av.x;
    As[ak + 1][arow] = av.y;
    #pragma unroll
    for (int qq = 0; qq < 4; ++qq)
      *(float4*)&Bs[bk][bc + qq * 4] = bv[qq];
    __syncthreads();
    #pragma unroll
    for (int k = 0; k < 16; ++k) {
      float4 a4 = *(const float4*)&As[k][ty * 4];
      float4 bA = *(const float4*)&Bs[k][tx * 4];
      float4 bB = *(const float4*)&Bs[k][tx * 4 + 128];
      float aj[4] = {a4.x, a4.y, a4.z, a4.w};
      float bi[8] = {bA.x, bA.y, bA.z, bA.w, bB.x, bB.y, bB.z, bB.w};
      #pragma unroll
      for (int j = 0; j < 4; ++j)
        #pragma unroll
        for (int i = 0; i < 8; ++i)
          acc[j][i] += aj[j] * bi[i];
    }
  }

  // epilogue: bias + relu + LayerNorm per row (256 cols across 32 tx lanes)
  float4 b2a = *(const float4*)&b2[tx * 4];
  float4 b2b = *(const float4*)&b2[tx * 4 + 128];
  float4 ga  = *(const float4*)&g[tx * 4];
  float4 gb  = *(const float4*)&g[tx * 4 + 128];
  float4 ba  = *(const float4*)&bb[tx * 4];
  float4 bbb = *(const float4*)&bb[tx * 4 + 128];
  const float bias8[8] = {b2a.x, b2a.y, b2a.z, b2a.w, b2b.x, b2b.y, b2b.z, b2b.w};
  const float g8[8]    = {ga.x, ga.y, ga.z, ga.w, gb.x, gb.y, gb.z, gb.w};
  const float be8[8]   = {ba.x, ba.y, ba.z, ba.w, bbb.x, bbb.y, bbb.z, bbb.w};

  #pragma unroll
  for (int j = 0; j < 4; ++j) {
    float v[8];
    float s = 0.f, sq = 0.f;
    #pragma unroll
    for (int i = 0; i < 8; ++i) {
      v[i] = fmaxf(acc[j][i] + bias8[i], 0.f);
      s += v[i];
      sq += v[i] * v[i];
    }
    #pragma unroll
    for (int off = 16; off >= 1; off >>= 1) {
      s  += __shfl_xor(s, off, 32);
      sq += __shfl_xor(sq, off, 32);
    }
    const float mu = s * (1.f / 256.f);
    const float var = sq * (1.f / 256.f) - mu * mu;
    const float rs = rsqrtf(var + 1e-5f);
    const int row = n0 + ty * 4 + j;
    float4 oA = {(v[0] - mu) * rs * g8[0] + be8[0], (v[1] - mu) * rs * g8[1] + be8[1],
                 (v[2] - mu) * rs * g8[2] + be8[2], (v[3] - mu) * rs * g8[3] + be8[3]};
    float4 oB = {(v[4] - mu) * rs * g8[4] + be8[4], (v[5] - mu) * rs * g8[5] + be8[5],
                 (v[6] - mu) * rs * g8[6] + be8[6], (v[7] - mu) * rs * g8[7] + be8[7]};
    *(float4*)&Z[(size_t)row * FDIM + tx * 4] = oA;
    *(float4*)&Z[(size_t)row * FDIM + tx * 4 + 128] = oB;
  }
}

// ---------------------------------------------------------------------------
extern "C" void kernel_launch(void* const* d_in, const int* in_sizes, int n_in,
                              void* d_out, int out_size, void* d_ws, size_t ws_size,
                              hipStream_t stream) {
  (void)in_sizes; (void)n_in; (void)out_size; (void)ws_size;

  const float* agent   = (const float*)d_in[0];
  const float* rg      = (const float*)d_in[1];
  const float* W_K     = (const float*)d_in[2];
  const float* b_K     = (const float*)d_in[3];
  const float* W_V     = (const float*)d_in[4];
  const float* b_V     = (const float*)d_in[5];
  const float* W_Q     = (const float*)d_in[6];
  const float* b_Q     = (const float*)d_in[7];
  const float* q_scale = (const float*)d_in[8];
  const float* W_Y2    = (const float*)d_in[9];
  const float* b_Y2    = (const float*)d_in[10];
  const float* W_F1    = (const float*)d_in[11];
  const float* b_F1    = (const float*)d_in[12];
  const float* W_F2    = (const float*)d_in[13];
  const float* b_F2    = (const float*)d_in[14];
  const float* ln_g    = (const float*)d_in[15];
  const float* ln_b    = (const float*)d_in[16];

  float* out = (float*)d_out;
  float* Z  = out;                       // [A,T,F]      2,981,888
  float* Qh = out + 2981888;             // [T,H,A,D]    2,981,888
  float* Kh = out + 5963776;             // [T,H,R,D]   23,855,104
  float* Vh = out + 29818880;            // [T,H,R,D]   23,855,104

  float* Y1 = (float*)d_ws;              // [A,T,F]
  float* S  = Y1 + (size_t)11648 * 256;  // [A,T,F]
  float* F1 = S  + (size_t)11648 * 256;  // [A,T,KF]

  const dim3 blk(256);

  // K / V projections: N = R*T = 93184
  gemm64<0><<<dim3(4, 1456), blk, 0, stream>>>(rg, W_K, b_K, Kh, 93184, 256, 256, nullptr);
  gemm64<0><<<dim3(4, 1456), blk, 0, stream>>>(rg, W_V, b_V, Vh, 93184, 256, 256, nullptr);
  // Q projection: N = A*T = 11648
  gemm64<1><<<dim3(4, 182), blk, 0, stream>>>(agent, W_Q, b_Q, Qh, 11648, 256, 256, q_scale);

  // attention: one block per (t, h)
  attn_kernel<<<dim3(364), dim3(128), 0, stream>>>(Qh, Kh, Vh, Y1);

  // Y2 = relu(Y1 @ W_Y2 + b) + agent -> S
  gemm64<3><<<dim3(4, 182), blk, 0, stream>>>(Y1, W_Y2, b_Y2, S, 11648, 256, 256, agent);
  // F1 = relu(S @ W_F1 + b)
  gemm64<4><<<dim3(16, 182), blk, 0, stream>>>(S, W_F1, b_F1, F1, 11648, 1024, 256, nullptr);
  // F2 = relu(F1 @ W_F2 + b); Z = LayerNorm(F2)
  f2_ln_kernel<<<dim3(364), blk, 0, stream>>>(F1, W_F2, b_F2, ln_g, ln_b, Z);
}

// Round 2
// 1632.174 us; speedup vs baseline: 1.1273x; 1.1273x over previous
//
#include <hip/hip_runtime.h>

#define T91  91
#define FDIM 256
#define HNUM 4
#define DDIM 64
#define ANUM 128
#define RNUM 1024
#define KFDIM 1024

// ---------------------------------------------------------------------------
// Generic 64x64 tiled fp32 GEMM:  out = epilogue(A[N,K] @ B[K,M] + bias)
// MODE 0: K/V proj  -> relu, store permuted [T,H,RNUM,D]
// MODE 1: Q proj    -> relu * q_scale[d], store permuted [T,H,ANUM,D]
// MODE 3: Y2        -> relu + agent (aux), store row-major [N,M]
// MODE 4: F1        -> relu, store row-major [N,M]
// ---------------------------------------------------------------------------
template<int MODE>
__global__ __launch_bounds__(256) void gemm64(
    const float* __restrict__ A, const float* __restrict__ B,
    const float* __restrict__ bias, float* __restrict__ out,
    int N, int M, int K, const float* __restrict__ aux) {
  __shared__ float As[16][68];   // [k][row], padded
  __shared__ float Bs[16][64];   // [k][col]

  const int tid = threadIdx.x;
  const int tx = tid & 15;
  const int ty = tid >> 4;
  const int n0 = blockIdx.y * 64;
  const int m0 = blockIdx.x * 64;

  const int arow = tid >> 2;
  const int ak   = (tid & 3) * 4;
  const int bk   = tid >> 4;
  const int bcol = (tid & 15) * 4;

  float acc[4][4];
  #pragma unroll
  for (int j = 0; j < 4; ++j)
    #pragma unroll
    for (int i = 0; i < 4; ++i) acc[j][i] = 0.f;

  for (int k0 = 0; k0 < K; k0 += 16) {
    float4 av = *(const float4*)&A[(size_t)(n0 + arow) * K + k0 + ak];
    float4 bv = *(const float4*)&B[(size_t)(k0 + bk) * M + m0 + bcol];
    __syncthreads();
    As[ak + 0][arow] = av.x;
    As[ak + 1][arow] = av.y;
    As[ak + 2][arow] = av.z;
    As[ak + 3][arow] = av.w;
    *(float4*)&Bs[bk][bcol] = bv;
    __syncthreads();
    #pragma unroll
    for (int k = 0; k < 16; ++k) {
      float4 a4 = *(const float4*)&As[k][ty * 4];
      float4 b4 = *(const float4*)&Bs[k][tx * 4];
      float aj[4] = {a4.x, a4.y, a4.z, a4.w};
      float bi[4] = {b4.x, b4.y, b4.z, b4.w};
      #pragma unroll
      for (int j = 0; j < 4; ++j)
        #pragma unroll
        for (int i = 0; i < 4; ++i)
          acc[j][i] += aj[j] * bi[i];
    }
  }

  const int c0 = m0 + tx * 4;
  #pragma unroll
  for (int j = 0; j < 4; ++j) {
    const int n = n0 + ty * 4 + j;
    float v[4];
    #pragma unroll
    for (int i = 0; i < 4; ++i)
      v[i] = fmaxf(acc[j][i] + bias[c0 + i], 0.f);

    if (MODE == 0) {                 // K/V: n = r*T + t ; col = h*64 + d
      const int rr = n / T91, tt = n - rr * T91;
      const int h = c0 >> 6, d0 = c0 & 63;
      float4 o = {v[0], v[1], v[2], v[3]};
      *(float4*)&out[(((size_t)tt * HNUM + h) * RNUM + rr) * DDIM + d0] = o;
    } else if (MODE == 1) {          // Q: n = a*T + t ; scale by q_scale[d]
      const int ai = n / T91, tt = n - ai * T91;
      const int h = c0 >> 6, d0 = c0 & 63;
      float4 o = {v[0] * aux[d0 + 0], v[1] * aux[d0 + 1],
                  v[2] * aux[d0 + 2], v[3] * aux[d0 + 3]};
      *(float4*)&out[(((size_t)tt * HNUM + h) * ANUM + ai) * DDIM + d0] = o;
    } else if (MODE == 3) {          // Y2 + agent residual -> S
      float4 ag = *(const float4*)&aux[(size_t)n * FDIM + c0];
      float4 o = {v[0] + ag.x, v[1] + ag.y, v[2] + ag.z, v[3] + ag.w};
      *(float4*)&out[(size_t)n * FDIM + c0] = o;
    } else {                         // F1 plain relu
      float4 o = {v[0], v[1], v[2], v[3]};
      *(float4*)&out[(size_t)n * M + c0] = o;
    }
  }
}

// ---------------------------------------------------------------------------
// Attention stage 1: partial flash attention over an R-chunk of 256.
// grid (364, 4): block (th, g) handles r in [g*256, (g+1)*256).
// 128 threads, 1 query row per thread, online softmax over chunks of 32.
// Partial acc stored d-interleaved for coalescing: Pacc[thg][dq][a][4].
// Pml[thg][0][a] = m, Pml[thg][1][a] = l.
// ---------------------------------------------------------------------------
__global__ __launch_bounds__(128) void attn_partial(
    const float* __restrict__ Qh, const float* __restrict__ Kh,
    const float* __restrict__ Vh, float* __restrict__ Pacc,
    float* __restrict__ Pml) {
  const int th = blockIdx.x;          // t*4 + h
  const int g  = blockIdx.y;          // 0..3 (R-chunk)
  const int a  = threadIdx.x;         // 0..127

  __shared__ float Kl[32][64];
  __shared__ float Vl[32][64];

  float q[64], acc[64];
  const float* qp = Qh + ((size_t)th * ANUM + a) * DDIM;
  #pragma unroll
  for (int i = 0; i < 16; ++i) {
    float4 v = *(const float4*)&qp[i * 4];
    q[4 * i + 0] = v.x; q[4 * i + 1] = v.y; q[4 * i + 2] = v.z; q[4 * i + 3] = v.w;
  }
  #pragma unroll
  for (int d = 0; d < 64; ++d) acc[d] = 0.f;

  float m = -1e30f, l = 0.f;
  const float* Kb = Kh + (size_t)th * RNUM * DDIM;
  const float* Vb = Vh + (size_t)th * RNUM * DDIM;

  const int lr = a >> 2;              // 0..31
  const int lc = (a & 3) * 16;        // 0,16,32,48

  const int rbeg = g * 256;
  for (int r0 = rbeg; r0 < rbeg + 256; r0 += 32) {
    __syncthreads();
    #pragma unroll
    for (int qq = 0; qq < 4; ++qq) {
      *(float4*)&Kl[lr][lc + qq * 4] =
          *(const float4*)&Kb[(size_t)(r0 + lr) * DDIM + lc + qq * 4];
      *(float4*)&Vl[lr][lc + qq * 4] =
          *(const float4*)&Vb[(size_t)(r0 + lr) * DDIM + lc + qq * 4];
    }
    __syncthreads();

    float e[32];
    float em = -1e30f;
    #pragma unroll
    for (int r = 0; r < 32; ++r) {
      const float4* kp = (const float4*)&Kl[r][0];
      float s = 0.f;
      #pragma unroll
      for (int i = 0; i < 16; ++i) {
        float4 kv = kp[i];
        s += q[4 * i + 0] * kv.x + q[4 * i + 1] * kv.y
           + q[4 * i + 2] * kv.z + q[4 * i + 3] * kv.w;
      }
      e[r] = s * 0.5f;                // / sqrt(H) = / 2
      em = fmaxf(em, e[r]);
    }
    const float mn = fmaxf(m, em);
    const float f = __expf(m - mn);
    l *= f;
    #pragma unroll
    for (int d = 0; d < 64; ++d) acc[d] *= f;
    #pragma unroll
    for (int r = 0; r < 32; ++r) {
      const float p = __expf(e[r] - mn);
      l += p;
      const float4* vp = (const float4*)&Vl[r][0];
      #pragma unroll
      for (int i = 0; i < 16; ++i) {
        float4 vv = vp[i];
        acc[4 * i + 0] += p * vv.x; acc[4 * i + 1] += p * vv.y;
        acc[4 * i + 2] += p * vv.z; acc[4 * i + 3] += p * vv.w;
      }
    }
    m = mn;
  }

  const int thg = th * 4 + g;
  Pml[(size_t)thg * 256 + a] = m;
  Pml[(size_t)thg * 256 + 128 + a] = l;
  float* pp = Pacc + (size_t)thg * 8192;   // 16 dq * 128 a * 4
  #pragma unroll
  for (int dq = 0; dq < 16; ++dq) {
    float4 o = {acc[4 * dq + 0], acc[4 * dq + 1], acc[4 * dq + 2], acc[4 * dq + 3]};
    *(float4*)&pp[dq * 512 + a * 4] = o;
  }
}

// ---------------------------------------------------------------------------
// Attention stage 2: combine 4 partial online-softmax states, write Y1.
// grid 364, 128 threads (one per query row a).
// ---------------------------------------------------------------------------
__global__ __launch_bounds__(128) void attn_combine(
    const float* __restrict__ Pacc, const float* __restrict__ Pml,
    float* __restrict__ Y1) {
  const int th = blockIdx.x;
  const int t = th >> 2, h = th & 3;
  const int a = threadIdx.x;

  float m[4], l[4];
  #pragma unroll
  for (int g = 0; g < 4; ++g) {
    m[g] = Pml[(size_t)(th * 4 + g) * 256 + a];
    l[g] = Pml[(size_t)(th * 4 + g) * 256 + 128 + a];
  }
  float mn = fmaxf(fmaxf(m[0], m[1]), fmaxf(m[2], m[3]));
  float sc[4], L = 0.f;
  #pragma unroll
  for (int g = 0; g < 4; ++g) {
    sc[g] = __expf(m[g] - mn);
    L += sc[g] * l[g];
  }
  const float inv = 1.f / L;

  float acc[64];
  #pragma unroll
  for (int d = 0; d < 64; ++d) acc[d] = 0.f;
  #pragma unroll
  for (int g = 0; g < 4; ++g) {
    const float* pp = Pacc + (size_t)(th * 4 + g) * 8192;
    const float s = sc[g];
    #pragma unroll
    for (int dq = 0; dq < 16; ++dq) {
      float4 v = *(const float4*)&pp[dq * 512 + a * 4];
      acc[4 * dq + 0] += s * v.x; acc[4 * dq + 1] += s * v.y;
      acc[4 * dq + 2] += s * v.z; acc[4 * dq + 3] += s * v.w;
    }
  }

  float* yp = Y1 + ((size_t)a * T91 + t) * FDIM + h * DDIM;
  #pragma unroll
  for (int i = 0; i < 16; ++i) {
    float4 o = {acc[4 * i + 0] * inv, acc[4 * i + 1] * inv,
                acc[4 * i + 2] * inv, acc[4 * i + 3] * inv};
    *(float4*)&yp[i * 4] = o;
  }
}

// ---------------------------------------------------------------------------
// F2 = relu(F1 @ W_F2 + b), then LayerNorm -> Z.  BM=32, BN=256 (full row).
// ---------------------------------------------------------------------------
__global__ __launch_bounds__(256) void f2_ln_kernel(
    const float* __restrict__ F1b, const float* __restrict__ W2,
    const float* __restrict__ b2, const float* __restrict__ g,
    const float* __restrict__ bb, float* __restrict__ Z) {
  __shared__ float As[16][36];
  __shared__ float Bs[16][256];

  const int tid = threadIdx.x;
  const int tx = tid & 31;
  const int ty = tid >> 5;
  const int n0 = blockIdx.x * 32;

  const int arow = tid >> 3;
  const int ak   = (tid & 7) * 2;
  const int bk   = tid >> 4;
  const int bc   = (tid & 15) * 16;

  float acc[4][8];
  #pragma unroll
  for (int j = 0; j < 4; ++j)
    #pragma unroll
    for (int i = 0; i < 8; ++i) acc[j][i] = 0.f;

  for (int k0 = 0; k0 < KFDIM; k0 += 16) {
    float2 av = *(const float2*)&F1b[(size_t)(n0 + arow) * KFDIM + k0 + ak];
    float4 bv[4];
    #pragma unroll
    for (int qq = 0; qq < 4; ++qq)
      bv[qq] = *(const float4*)&W2[(size_t)(k0 + bk) * FDIM + bc + qq * 4];
    __syncthreads();
    As[ak + 0][arow] = av.x;
    As[ak + 1][arow] = av.y;
    #pragma unroll
    for (int qq = 0; qq < 4; ++qq)
      *(float4*)&Bs[bk][bc + qq * 4] = bv[qq];
    __syncthreads();
    #pragma unroll
    for (int k = 0; k < 16; ++k) {
      float4 a4 = *(const float4*)&As[k][ty * 4];
      float4 bA = *(const float4*)&Bs[k][tx * 4];
      float4 bB = *(const float4*)&Bs[k][tx * 4 + 128];
      float aj[4] = {a4.x, a4.y, a4.z, a4.w};
      float bi[8] = {bA.x, bA.y, bA.z, bA.w, bB.x, bB.y, bB.z, bB.w};
      #pragma unroll
      for (int j = 0; j < 4; ++j)
        #pragma unroll
        for (int i = 0; i < 8; ++i)
          acc[j][i] += aj[j] * bi[i];
    }
  }

  float4 b2a = *(const float4*)&b2[tx * 4];
  float4 b2b = *(const float4*)&b2[tx * 4 + 128];
  float4 ga  = *(const float4*)&g[tx * 4];
  float4 gb  = *(const float4*)&g[tx * 4 + 128];
  float4 ba  = *(const float4*)&bb[tx * 4];
  float4 bbb = *(const float4*)&bb[tx * 4 + 128];
  const float bias8[8] = {b2a.x, b2a.y, b2a.z, b2a.w, b2b.x, b2b.y, b2b.z, b2b.w};
  const float g8[8]    = {ga.x, ga.y, ga.z, ga.w, gb.x, gb.y, gb.z, gb.w};
  const float be8[8]   = {ba.x, ba.y, ba.z, ba.w, bbb.x, bbb.y, bbb.z, bbb.w};

  #pragma unroll
  for (int j = 0; j < 4; ++j) {
    float v[8];
    float s = 0.f, sq = 0.f;
    #pragma unroll
    for (int i = 0; i < 8; ++i) {
      v[i] = fmaxf(acc[j][i] + bias8[i], 0.f);
      s += v[i];
      sq += v[i] * v[i];
    }
    #pragma unroll
    for (int off = 16; off >= 1; off >>= 1) {
      s  += __shfl_xor(s, off, 32);
      sq += __shfl_xor(sq, off, 32);
    }
    const float mu = s * (1.f / 256.f);
    const float var = sq * (1.f / 256.f) - mu * mu;
    const float rs = rsqrtf(var + 1e-5f);
    const int row = n0 + ty * 4 + j;
    float4 oA = {(v[0] - mu) * rs * g8[0] + be8[0], (v[1] - mu) * rs * g8[1] + be8[1],
                 (v[2] - mu) * rs * g8[2] + be8[2], (v[3] - mu) * rs * g8[3] + be8[3]};
    float4 oB = {(v[4] - mu) * rs * g8[4] + be8[4], (v[5] - mu) * rs * g8[5] + be8[5],
                 (v[6] - mu) * rs * g8[6] + be8[6], (v[7] - mu) * rs * g8[7] + be8[7]};
    *(float4*)&Z[(size_t)row * FDIM + tx * 4] = oA;
    *(float4*)&Z[(size_t)row * FDIM + tx * 4 + 128] = oB;
  }
}

// ---------------------------------------------------------------------------
extern "C" void kernel_launch(void* const* d_in, const int* in_sizes, int n_in,
                              void* d_out, int out_size, void* d_ws, size_t ws_size,
                              hipStream_t stream) {
  (void)in_sizes; (void)n_in; (void)out_size; (void)ws_size;

  const float* agent   = (const float*)d_in[0];
  const float* rg      = (const float*)d_in[1];
  const float* W_K     = (const float*)d_in[2];
  const float* b_K     = (const float*)d_in[3];
  const float* W_V     = (const float*)d_in[4];
  const float* b_V     = (const float*)d_in[5];
  const float* W_Q     = (const float*)d_in[6];
  const float* b_Q     = (const float*)d_in[7];
  const float* q_scale = (const float*)d_in[8];
  const float* W_Y2    = (const float*)d_in[9];
  const float* b_Y2    = (const float*)d_in[10];
  const float* W_F1    = (const float*)d_in[11];
  const float* b_F1    = (const float*)d_in[12];
  const float* W_F2    = (const float*)d_in[13];
  const float* b_F2    = (const float*)d_in[14];
  const float* ln_g    = (const float*)d_in[15];
  const float* ln_b    = (const float*)d_in[16];

  float* out = (float*)d_out;
  float* Z  = out;                       // [A,T,F]
  float* Qh = out + 2981888;             // [T,H,A,D]
  float* Kh = out + 5963776;             // [T,H,R,D]
  float* Vh = out + 29818880;            // [T,H,R,D]

  float* Y1 = (float*)d_ws;              // [A,T,F]      11.9 MB
  float* S  = Y1 + (size_t)11648 * 256;  // [A,T,F]      11.9 MB
  float* F1 = S  + (size_t)11648 * 256;  // [A,T,KF]     47.7 MB
  // Attention partial buffers alias regions that are dead during attention:
  float* Pacc = F1;                      // 1456*8192 floats = 47.7 MB (= F1 size)
  float* Pml  = S;                       // 1456*256 floats = 1.5 MB (< S size)

  const dim3 blk(256);

  // K / V projections: N = R*T = 93184
  gemm64<0><<<dim3(4, 1456), blk, 0, stream>>>(rg, W_K, b_K, Kh, 93184, 256, 256, nullptr);
  gemm64<0><<<dim3(4, 1456), blk, 0, stream>>>(rg, W_V, b_V, Vh, 93184, 256, 256, nullptr);
  // Q projection: N = A*T = 11648
  gemm64<1><<<dim3(4, 182), blk, 0, stream>>>(agent, W_Q, b_Q, Qh, 11648, 256, 256, q_scale);

  // attention: stage 1 partials over R-chunks of 256, stage 2 combine
  attn_partial<<<dim3(364, 4), dim3(128), 0, stream>>>(Qh, Kh, Vh, Pacc, Pml);
  attn_combine<<<dim3(364), dim3(128), 0, stream>>>(Pacc, Pml, Y1);

  // Y2 = relu(Y1 @ W_Y2 + b) + agent -> S   (S overwrites Pml region: attn done)
  gemm64<3><<<dim3(4, 182), blk, 0, stream>>>(Y1, W_Y2, b_Y2, S, 11648, 256, 256, agent);
  // F1 = relu(S @ W_F1 + b)                 (F1 overwrites Pacc region: attn done)
  gemm64<4><<<dim3(16, 182), blk, 0, stream>>>(S, W_F1, b_F1, F1, 11648, 1024, 256, nullptr);
  // F2 = relu(F1 @ W_F2 + b); Z = LayerNorm(F2)
  f2_ln_kernel<<<dim3(364), blk, 0, stream>>>(F1, W_F2, b_F2, ln_g, ln_b, Z);
}

// Round 3
// 1033.363 us; speedup vs baseline: 1.7806x; 1.5795x over previous
//
#include <hip/hip_runtime.h>

#define T91  91
#define FDIM 256
#define HNUM 4
#define DDIM 64
#define ANUM 128
#define RNUM 1024
#define KFDIM 1024

typedef __attribute__((ext_vector_type(8))) short short8v;
typedef __attribute__((ext_vector_type(4))) float f32x4;

__device__ __forceinline__ ushort f2bf(float f) {
  union { float f; uint32_t u; } c; c.f = f;
  return (ushort)((c.u + 0x7FFFu + ((c.u >> 16) & 1u)) >> 16);
}

// ---------------------------------------------------------------------------
// Generic 64x64 tiled fp32 GEMM:  out = epilogue(A[N,K] @ B[K,M] + bias)
// MODE 0: K proj  -> relu, store permuted [T,H,R,D]
// MODE 5: V proj  -> relu, store permuted [T,H,R,D] + bf16 V^T [T,H,D,R] (aux)
// MODE 1: Q proj  -> relu * q_scale[d], store permuted [T,H,A,D]
// MODE 3: Y2      -> relu + agent (aux), row-major
// MODE 4: F1      -> relu, row-major
// ---------------------------------------------------------------------------
template<int MODE>
__global__ __launch_bounds__(256) void gemm64(
    const float* __restrict__ A, const float* __restrict__ B,
    const float* __restrict__ bias, float* __restrict__ out,
    int N, int M, int K, const float* __restrict__ aux) {
  __shared__ float As[16][68];
  __shared__ float Bs[16][64];

  const int tid = threadIdx.x;
  const int tx = tid & 15;
  const int ty = tid >> 4;
  const int n0 = blockIdx.y * 64;
  const int m0 = blockIdx.x * 64;

  const int arow = tid >> 2;
  const int ak   = (tid & 3) * 4;
  const int bk   = tid >> 4;
  const int bcol = (tid & 15) * 4;

  float acc[4][4];
  #pragma unroll
  for (int j = 0; j < 4; ++j)
    #pragma unroll
    for (int i = 0; i < 4; ++i) acc[j][i] = 0.f;

  for (int k0 = 0; k0 < K; k0 += 16) {
    float4 av = *(const float4*)&A[(size_t)(n0 + arow) * K + k0 + ak];
    float4 bv = *(const float4*)&B[(size_t)(k0 + bk) * M + m0 + bcol];
    __syncthreads();
    As[ak + 0][arow] = av.x;
    As[ak + 1][arow] = av.y;
    As[ak + 2][arow] = av.z;
    As[ak + 3][arow] = av.w;
    *(float4*)&Bs[bk][bcol] = bv;
    __syncthreads();
    #pragma unroll
    for (int k = 0; k < 16; ++k) {
      float4 a4 = *(const float4*)&As[k][ty * 4];
      float4 b4 = *(const float4*)&Bs[k][tx * 4];
      float aj[4] = {a4.x, a4.y, a4.z, a4.w};
      float bi[4] = {b4.x, b4.y, b4.z, b4.w};
      #pragma unroll
      for (int j = 0; j < 4; ++j)
        #pragma unroll
        for (int i = 0; i < 4; ++i)
          acc[j][i] += aj[j] * bi[i];
    }
  }

  const int c0 = m0 + tx * 4;
  #pragma unroll
  for (int j = 0; j < 4; ++j) {
    const int n = n0 + ty * 4 + j;
    float v[4];
    #pragma unroll
    for (int i = 0; i < 4; ++i)
      v[i] = fmaxf(acc[j][i] + bias[c0 + i], 0.f);

    if (MODE == 0 || MODE == 5) {    // K/V: n = r*T + t ; col = h*64 + d
      const int rr = n / T91, tt = n - rr * T91;
      const int h = c0 >> 6, d0 = c0 & 63;
      float4 o = {v[0], v[1], v[2], v[3]};
      *(float4*)&out[(((size_t)tt * HNUM + h) * RNUM + rr) * DDIM + d0] = o;
      if (MODE == 5) {               // also bf16 V^T: [th][d][r]
        ushort* vt = (ushort*)aux;
        const size_t tb = ((size_t)(tt * HNUM + h) * DDIM) * RNUM;
        #pragma unroll
        for (int i = 0; i < 4; ++i)
          vt[tb + (size_t)(d0 + i) * RNUM + rr] = f2bf(v[i]);
      }
    } else if (MODE == 1) {          // Q: n = a*T + t ; scale by q_scale[d]
      const int ai = n / T91, tt = n - ai * T91;
      const int h = c0 >> 6, d0 = c0 & 63;
      float4 o = {v[0] * aux[d0 + 0], v[1] * aux[d0 + 1],
                  v[2] * aux[d0 + 2], v[3] * aux[d0 + 3]};
      *(float4*)&out[(((size_t)tt * HNUM + h) * ANUM + ai) * DDIM + d0] = o;
    } else if (MODE == 3) {          // Y2 + agent residual -> S
      float4 ag = *(const float4*)&aux[(size_t)n * FDIM + c0];
      float4 o = {v[0] + ag.x, v[1] + ag.y, v[2] + ag.z, v[3] + ag.w};
      *(float4*)&out[(size_t)n * FDIM + c0] = o;
    } else {                         // F1 plain relu
      float4 o = {v[0], v[1], v[2], v[3]};
      *(float4*)&out[(size_t)n * M + c0] = o;
    }
  }
}

// ---------------------------------------------------------------------------
// MFMA flash attention, stage 1. grid (364, 2): (t*4+h, R-half of 512).
// 4 waves x 32 q-rows. Per 64-r tile: K (fp32->bf16, swizzled LDS), V^T
// (pre-swizzled bf16 global -> linear LDS), QK^T via 16x16x32 bf16 MFMA,
// online softmax in C-fragment layout, P via LDS round-trip, PV MFMA.
// Outputs: Pacc[thg][q 128][d 64] (unnormalized), Pml[thg][{m,l} x 128].
// ---------------------------------------------------------------------------
__global__ __launch_bounds__(256) void attn_mfma(
    const float* __restrict__ Qh, const float* __restrict__ Kh,
    const ushort* __restrict__ Vt, float* __restrict__ Pacc,
    float* __restrict__ Pml) {
  const int th = blockIdx.x, g = blockIdx.y;
  const int tid = threadIdx.x;
  const int wid = tid >> 6, lane = tid & 63;
  const int lg = lane >> 4, li = lane & 15;

  __shared__ ushort Kl[4096];   // [r 64][d 64] bf16, rows XOR-swizzled
  __shared__ ushort Vl[4096];   // V^T [d 64][r 64] bf16, rows XOR-swizzled
  __shared__ ushort Pl[8192];   // 4 waves x [q 32][r 64] bf16, swizzled

  // Q A-fragments, x0.5 (the 1/sqrt(H) scale)
  short8v qf[2][2];
  #pragma unroll
  for (int qsub = 0; qsub < 2; ++qsub)
    #pragma unroll
    for (int kc = 0; kc < 2; ++kc) {
      const float* qp = Qh + ((size_t)th * ANUM + wid * 32 + qsub * 16 + li) * DDIM + kc * 32 + lg * 8;
      float4 x = *(const float4*)qp;
      float4 y = *(const float4*)(qp + 4);
      short8v v;
      v[0] = (short)f2bf(x.x * 0.5f); v[1] = (short)f2bf(x.y * 0.5f);
      v[2] = (short)f2bf(x.z * 0.5f); v[3] = (short)f2bf(x.w * 0.5f);
      v[4] = (short)f2bf(y.x * 0.5f); v[5] = (short)f2bf(y.y * 0.5f);
      v[6] = (short)f2bf(y.z * 0.5f); v[7] = (short)f2bf(y.w * 0.5f);
      qf[qsub][kc] = v;
    }

  f32x4 yacc[2][4];
  #pragma unroll
  for (int a = 0; a < 2; ++a)
    #pragma unroll
    for (int b = 0; b < 4; ++b)
      #pragma unroll
      for (int i = 0; i < 4; ++i) yacc[a][b][i] = 0.f;

  float mrow[2][4], lrow[2][4];
  #pragma unroll
  for (int a = 0; a < 2; ++a)
    #pragma unroll
    for (int i = 0; i < 4; ++i) { mrow[a][i] = -1e30f; lrow[a][i] = 0.f; }

  const float*  Kb = Kh + (size_t)th * RNUM * DDIM;
  const ushort* Vb = Vt + (size_t)th * DDIM * RNUM;

  const int krr = wid * 16 + (lane >> 2);   // K-stage row (0..63)
  const int kd0 = (lane & 3) * 16;          // K-stage d offset

  for (int tt = 0; tt < 8; ++tt) {
    const int r0 = g * 512 + tt * 64;
    __syncthreads();
    // ---- stage K tile (fp32 -> bf16, swizzled) ----
    {
      const float* kp = Kb + (size_t)(r0 + krr) * DDIM + kd0;
      float4 a = *(const float4*)kp,       b = *(const float4*)(kp + 4),
             c = *(const float4*)(kp + 8), d = *(const float4*)(kp + 12);
      short8v v0, v1;
      v0[0] = (short)f2bf(a.x); v0[1] = (short)f2bf(a.y);
      v0[2] = (short)f2bf(a.z); v0[3] = (short)f2bf(a.w);
      v0[4] = (short)f2bf(b.x); v0[5] = (short)f2bf(b.y);
      v0[6] = (short)f2bf(b.z); v0[7] = (short)f2bf(b.w);
      v1[0] = (short)f2bf(c.x); v1[1] = (short)f2bf(c.y);
      v1[2] = (short)f2bf(c.z); v1[3] = (short)f2bf(c.w);
      v1[4] = (short)f2bf(d.x); v1[5] = (short)f2bf(d.y);
      v1[6] = (short)f2bf(d.z); v1[7] = (short)f2bf(d.w);
      const int base = krr * 128 + kd0 * 2;
      const int sw = (krr & 7) << 4;
      *(short8v*)((char*)Kl + (base ^ sw)) = v0;
      *(short8v*)((char*)Kl + ((base + 16) ^ sw)) = v1;
    }
    // ---- stage V^T tile (pre-swizzled global src -> linear LDS) ----
    #pragma unroll
    for (int c = 0; c < 2; ++c) {
      const int B = (wid * 2 + c) * 1024 + lane * 16;   // dest byte
      const int dd = B >> 7, o = B & 127;
      const ushort* sp = Vb + (size_t)dd * RNUM + r0 + ((o ^ ((dd & 7) << 4)) >> 1);
      short8v v = *(const short8v*)sp;
      *(short8v*)((char*)Vl + B) = v;
    }
    __syncthreads();

    // ---- QK^T ----
    f32x4 sf[2][4];
    #pragma unroll
    for (int a = 0; a < 2; ++a)
      #pragma unroll
      for (int b = 0; b < 4; ++b)
        #pragma unroll
        for (int i = 0; i < 4; ++i) sf[a][b][i] = 0.f;

    #pragma unroll
    for (int kc = 0; kc < 2; ++kc) {
      short8v kf[4];
      #pragma unroll
      for (int rsub = 0; rsub < 4; ++rsub) {
        const int rl = rsub * 16 + li;
        kf[rsub] = *(const short8v*)((char*)Kl + ((rl * 128 + kc * 64 + lg * 16) ^ ((rl & 7) << 4)));
      }
      #pragma unroll
      for (int qsub = 0; qsub < 2; ++qsub)
        #pragma unroll
        for (int rsub = 0; rsub < 4; ++rsub)
          sf[qsub][rsub] = __builtin_amdgcn_mfma_f32_16x16x32_bf16(
              qf[qsub][kc], kf[rsub], sf[qsub][rsub], 0, 0, 0);
    }

    // ---- online softmax (C-layout: row = lg*4+i, col = li) ----
    #pragma unroll
    for (int qsub = 0; qsub < 2; ++qsub)
      #pragma unroll
      for (int i = 0; i < 4; ++i) {
        float em = fmaxf(fmaxf(sf[qsub][0][i], sf[qsub][1][i]),
                         fmaxf(sf[qsub][2][i], sf[qsub][3][i]));
        em = fmaxf(em, __shfl_xor(em, 1));
        em = fmaxf(em, __shfl_xor(em, 2));
        em = fmaxf(em, __shfl_xor(em, 4));
        em = fmaxf(em, __shfl_xor(em, 8));
        const float mn = fmaxf(mrow[qsub][i], em);
        const float fs = __expf(mrow[qsub][i] - mn);
        mrow[qsub][i] = mn;
        const float p0 = __expf(sf[qsub][0][i] - mn);
        const float p1 = __expf(sf[qsub][1][i] - mn);
        const float p2 = __expf(sf[qsub][2][i] - mn);
        const float p3 = __expf(sf[qsub][3][i] - mn);
        float rs = p0 + p1 + p2 + p3;
        rs += __shfl_xor(rs, 1);
        rs += __shfl_xor(rs, 2);
        rs += __shfl_xor(rs, 4);
        rs += __shfl_xor(rs, 8);
        lrow[qsub][i] = lrow[qsub][i] * fs + rs;
        #pragma unroll
        for (int dsub = 0; dsub < 4; ++dsub) yacc[qsub][dsub][i] *= fs;
        // write P (bf16) into per-wave LDS region, swizzled rows
        const int q = qsub * 16 + lg * 4 + i;
        const int sw = (q & 7) << 4;
        char* pb = (char*)Pl + wid * 4096;
        *(ushort*)(pb + ((q * 128 + (0 * 16 + li) * 2) ^ sw)) = f2bf(p0);
        *(ushort*)(pb + ((q * 128 + (1 * 16 + li) * 2) ^ sw)) = f2bf(p1);
        *(ushort*)(pb + ((q * 128 + (2 * 16 + li) * 2) ^ sw)) = f2bf(p2);
        *(ushort*)(pb + ((q * 128 + (3 * 16 + li) * 2) ^ sw)) = f2bf(p3);
      }

    // ---- PV ----
    #pragma unroll
    for (int rc = 0; rc < 2; ++rc) {
      short8v pa[2];
      #pragma unroll
      for (int qsub = 0; qsub < 2; ++qsub) {
        const int qq = qsub * 16 + li;
        pa[qsub] = *(const short8v*)((char*)Pl + wid * 4096 +
                    ((qq * 128 + rc * 64 + lg * 16) ^ ((qq & 7) << 4)));
      }
      #pragma unroll
      for (int dsub = 0; dsub < 4; ++dsub) {
        const int dd = dsub * 16 + li;
        short8v vb = *(const short8v*)((char*)Vl +
                      ((dd * 128 + rc * 64 + lg * 16) ^ ((dd & 7) << 4)));
        #pragma unroll
        for (int qsub = 0; qsub < 2; ++qsub)
          yacc[qsub][dsub] = __builtin_amdgcn_mfma_f32_16x16x32_bf16(
              pa[qsub], vb, yacc[qsub][dsub], 0, 0, 0);
      }
    }
  }

  // ---- partial outputs ----
  const int thg = th * 2 + g;
  float* pp = Pacc + (size_t)thg * 8192;
  #pragma unroll
  for (int qsub = 0; qsub < 2; ++qsub)
    #pragma unroll
    for (int dsub = 0; dsub < 4; ++dsub)
      #pragma unroll
      for (int i = 0; i < 4; ++i) {
        const int q = wid * 32 + qsub * 16 + lg * 4 + i;
        pp[q * 64 + dsub * 16 + li] = yacc[qsub][dsub][i];
      }
  if (li == 0) {
    #pragma unroll
    for (int qsub = 0; qsub < 2; ++qsub)
      #pragma unroll
      for (int i = 0; i < 4; ++i) {
        const int q = wid * 32 + qsub * 16 + lg * 4 + i;
        Pml[(size_t)thg * 256 + q] = mrow[qsub][i];
        Pml[(size_t)thg * 256 + 128 + q] = lrow[qsub][i];
      }
  }
}

// ---------------------------------------------------------------------------
// Attention stage 2: combine the 2 R-half partials, normalize, write Y1.
// ---------------------------------------------------------------------------
__global__ __launch_bounds__(128) void attn_combine(
    const float* __restrict__ Pacc, const float* __restrict__ Pml,
    float* __restrict__ Y1) {
  const int th = blockIdx.x;
  const int t = th >> 2, h = th & 3;
  const int a = threadIdx.x;
  const float m0 = Pml[(size_t)(th * 2 + 0) * 256 + a];
  const float l0 = Pml[(size_t)(th * 2 + 0) * 256 + 128 + a];
  const float m1 = Pml[(size_t)(th * 2 + 1) * 256 + a];
  const float l1 = Pml[(size_t)(th * 2 + 1) * 256 + 128 + a];
  const float mn = fmaxf(m0, m1);
  const float s0 = __expf(m0 - mn), s1 = __expf(m1 - mn);
  const float inv = 1.f / (s0 * l0 + s1 * l1);
  const float* p0 = Pacc + (size_t)(th * 2 + 0) * 8192 + a * 64;
  const float* p1 = Pacc + (size_t)(th * 2 + 1) * 8192 + a * 64;
  float* yp = Y1 + ((size_t)a * T91 + t) * FDIM + h * DDIM;
  #pragma unroll
  for (int i = 0; i < 16; ++i) {
    float4 v0 = *(const float4*)(p0 + i * 4);
    float4 v1 = *(const float4*)(p1 + i * 4);
    float4 o = {(s0 * v0.x + s1 * v1.x) * inv, (s0 * v0.y + s1 * v1.y) * inv,
                (s0 * v0.z + s1 * v1.z) * inv, (s0 * v0.w + s1 * v1.w) * inv};
    *(float4*)(yp + i * 4) = o;
  }
}

// ---------------------------------------------------------------------------
// F2 = relu(F1 @ W_F2 + b), then LayerNorm -> Z.  BM=32, BN=256 (full row).
// ---------------------------------------------------------------------------
__global__ __launch_bounds__(256) void f2_ln_kernel(
    const float* __restrict__ F1b, const float* __restrict__ W2,
    const float* __restrict__ b2, const float* __restrict__ g,
    const float* __restrict__ bb, float* __restrict__ Z) {
  __shared__ float As[16][36];
  __shared__ float Bs[16][256];

  const int tid = threadIdx.x;
  const int tx = tid & 31;
  const int ty = tid >> 5;
  const int n0 = blockIdx.x * 32;

  const int arow = tid >> 3;
  const int ak   = (tid & 7) * 2;
  const int bk   = tid >> 4;
  const int bc   = (tid & 15) * 16;

  float acc[4][8];
  #pragma unroll
  for (int j = 0; j < 4; ++j)
    #pragma unroll
    for (int i = 0; i < 8; ++i) acc[j][i] = 0.f;

  for (int k0 = 0; k0 < KFDIM; k0 += 16) {
    float2 av = *(const float2*)&F1b[(size_t)(n0 + arow) * KFDIM + k0 + ak];
    float4 bv[4];
    #pragma unroll
    for (int qq = 0; qq < 4; ++qq)
      bv[qq] = *(const float4*)&W2[(size_t)(k0 + bk) * FDIM + bc + qq * 4];
    __syncthreads();
    As[ak + 0][arow] = av.x;
    As[ak + 1][arow] = av.y;
    #pragma unroll
    for (int qq = 0; qq < 4; ++qq)
      *(float4*)&Bs[bk][bc + qq * 4] = bv[qq];
    __syncthreads();
    #pragma unroll
    for (int k = 0; k < 16; ++k) {
      float4 a4 = *(const float4*)&As[k][ty * 4];
      float4 bA = *(const float4*)&Bs[k][tx * 4];
      float4 bB = *(const float4*)&Bs[k][tx * 4 + 128];
      float aj[4] = {a4.x, a4.y, a4.z, a4.w};
      float bi[8] = {bA.x, bA.y, bA.z, bA.w, bB.x, bB.y, bB.z, bB.w};
      #pragma unroll
      for (int j = 0; j < 4; ++j)
        #pragma unroll
        for (int i = 0; i < 8; ++i)
          acc[j][i] += aj[j] * bi[i];
    }
  }

  float4 b2a = *(const float4*)&b2[tx * 4];
  float4 b2b = *(const float4*)&b2[tx * 4 + 128];
  float4 ga  = *(const float4*)&g[tx * 4];
  float4 gb  = *(const float4*)&g[tx * 4 + 128];
  float4 ba  = *(const float4*)&bb[tx * 4];
  float4 bbb = *(const float4*)&bb[tx * 4 + 128];
  const float bias8[8] = {b2a.x, b2a.y, b2a.z, b2a.w, b2b.x, b2b.y, b2b.z, b2b.w};
  const float g8[8]    = {ga.x, ga.y, ga.z, ga.w, gb.x, gb.y, gb.z, gb.w};
  const float be8[8]   = {ba.x, ba.y, ba.z, ba.w, bbb.x, bbb.y, bbb.z, bbb.w};

  #pragma unroll
  for (int j = 0; j < 4; ++j) {
    float v[8];
    float s = 0.f, sq = 0.f;
    #pragma unroll
    for (int i = 0; i < 8; ++i) {
      v[i] = fmaxf(acc[j][i] + bias8[i], 0.f);
      s += v[i];
      sq += v[i] * v[i];
    }
    #pragma unroll
    for (int off = 16; off >= 1; off >>= 1) {
      s  += __shfl_xor(s, off, 32);
      sq += __shfl_xor(sq, off, 32);
    }
    const float mu = s * (1.f / 256.f);
    const float var = sq * (1.f / 256.f) - mu * mu;
    const float rs = rsqrtf(var + 1e-5f);
    const int row = n0 + ty * 4 + j;
    float4 oA = {(v[0] - mu) * rs * g8[0] + be8[0], (v[1] - mu) * rs * g8[1] + be8[1],
                 (v[2] - mu) * rs * g8[2] + be8[2], (v[3] - mu) * rs * g8[3] + be8[3]};
    float4 oB = {(v[4] - mu) * rs * g8[4] + be8[4], (v[5] - mu) * rs * g8[5] + be8[5],
                 (v[6] - mu) * rs * g8[6] + be8[6], (v[7] - mu) * rs * g8[7] + be8[7]};
    *(float4*)&Z[(size_t)row * FDIM + tx * 4] = oA;
    *(float4*)&Z[(size_t)row * FDIM + tx * 4 + 128] = oB;
  }
}

// ---------------------------------------------------------------------------
extern "C" void kernel_launch(void* const* d_in, const int* in_sizes, int n_in,
                              void* d_out, int out_size, void* d_ws, size_t ws_size,
                              hipStream_t stream) {
  (void)in_sizes; (void)n_in; (void)out_size; (void)ws_size;

  const float* agent   = (const float*)d_in[0];
  const float* rg      = (const float*)d_in[1];
  const float* W_K     = (const float*)d_in[2];
  const float* b_K     = (const float*)d_in[3];
  const float* W_V     = (const float*)d_in[4];
  const float* b_V     = (const float*)d_in[5];
  const float* W_Q     = (const float*)d_in[6];
  const float* b_Q     = (const float*)d_in[7];
  const float* q_scale = (const float*)d_in[8];
  const float* W_Y2    = (const float*)d_in[9];
  const float* b_Y2    = (const float*)d_in[10];
  const float* W_F1    = (const float*)d_in[11];
  const float* b_F1    = (const float*)d_in[12];
  const float* W_F2    = (const float*)d_in[13];
  const float* b_F2    = (const float*)d_in[14];
  const float* ln_g    = (const float*)d_in[15];
  const float* ln_b    = (const float*)d_in[16];

  float* out = (float*)d_out;
  float* Z  = out;                       // [A,T,F]
  float* Qh = out + 2981888;             // [T,H,A,D]
  float* Kh = out + 5963776;             // [T,H,R,D]
  float* Vh = out + 29818880;            // [T,H,R,D]

  // workspace layout (107.3 MB):
  //   S   : 2,981,888 f  (alias: Pml during attention)
  //   F1  : 11,927,552 f (alias: Pacc during attention)
  //   Vt  : 23,855,104 ushort bf16 V^T (alias: Y1 after attention)
  float* S    = (float*)d_ws;
  float* F1   = S + 2981888;
  ushort* Vt  = (ushort*)(F1 + 11927552);
  float* Y1   = (float*)Vt;              // written by combine, after Vt is dead
  float* Pacc = F1;                      // 728*8192 f = 23.9 MB <= F1
  float* Pml  = S;                       // 728*256 f <= S

  const dim3 blk(256);

  // K / V projections: N = R*T = 93184
  gemm64<0><<<dim3(4, 1456), blk, 0, stream>>>(rg, W_K, b_K, Kh, 93184, 256, 256, nullptr);
  gemm64<5><<<dim3(4, 1456), blk, 0, stream>>>(rg, W_V, b_V, Vh, 93184, 256, 256, (const float*)Vt);
  // Q projection: N = A*T = 11648
  gemm64<1><<<dim3(4, 182), blk, 0, stream>>>(agent, W_Q, b_Q, Qh, 11648, 256, 256, q_scale);

  // attention: MFMA partials over 2 R-halves, then combine
  attn_mfma<<<dim3(364, 2), blk, 0, stream>>>(Qh, Kh, Vt, Pacc, Pml);
  attn_combine<<<dim3(364), dim3(128), 0, stream>>>(Pacc, Pml, Y1);

  // Y2 = relu(Y1 @ W_Y2 + b) + agent -> S
  gemm64<3><<<dim3(4, 182), blk, 0, stream>>>(Y1, W_Y2, b_Y2, S, 11648, 256, 256, agent);
  // F1 = relu(S @ W_F1 + b)
  gemm64<4><<<dim3(16, 182), blk, 0, stream>>>(S, W_F1, b_F1, F1, 11648, 1024, 256, nullptr);
  // F2 = relu(F1 @ W_F2 + b); Z = LayerNorm(F2)
  f2_ln_kernel<<<dim3(364), blk, 0, stream>>>(F1, W_F2, b_F2, ln_g, ln_b, Z);
}

// Round 5
// 557.046 us; speedup vs baseline: 3.3031x; 1.8551x over previous
//
#include <hip/hip_runtime.h>

#define T91  91
#define FDIM 256
#define HNUM 4
#define DDIM 64
#define ANUM 128
#define RNUM 1024
#define KFDIM 1024

typedef __attribute__((ext_vector_type(8))) short short8v;
typedef __attribute__((ext_vector_type(4))) float f32x4;

__device__ __forceinline__ ushort f2bf(float f) {
  union { float f; uint32_t u; } c; c.f = f;
  return (ushort)((c.u + 0x7FFFu + ((c.u >> 16) & 1u)) >> 16);
}
__device__ __forceinline__ short8v pack8(float4 a, float4 b) {
  short8v v;
  v[0] = (short)f2bf(a.x); v[1] = (short)f2bf(a.y);
  v[2] = (short)f2bf(a.z); v[3] = (short)f2bf(a.w);
  v[4] = (short)f2bf(b.x); v[5] = (short)f2bf(b.y);
  v[6] = (short)f2bf(b.z); v[7] = (short)f2bf(b.w);
  return v;
}

// ---------------------------------------------------------------------------
// Weight transpose+convert: Wt[m][k] = bf16(W[k][m]).
// ---------------------------------------------------------------------------
__global__ __launch_bounds__(256) void wconv(
    const float* __restrict__ W, ushort* __restrict__ Wt, int Kd, int Md, int total) {
  const int o = blockIdx.x * 256 + threadIdx.x;
  if (o >= total) return;
  const int m = o / Kd, k = o - m * Kd;
  Wt[o] = f2bf(W[(size_t)k * Md + m]);
}

// ---------------------------------------------------------------------------
// K/V projection, MFMA.  Block = fixed t, 64 r-rows, all 256 cols.
// 4 waves; wave wid owns cols h=wid.  Out: fp32 [T,H,R,D].
// ISV: also emit bf16 V^T tiles Vt[th][rt][d 64][r 64].
// ---------------------------------------------------------------------------
template<int ISV>
__global__ __launch_bounds__(256) void kvproj_mfma(
    const float* __restrict__ rg, const ushort* __restrict__ Wt,
    const float* __restrict__ bias, float* __restrict__ outKV,
    ushort* __restrict__ Vt) {
  const int rt = blockIdx.x;          // 0..15
  const int tfix = blockIdx.y;        // 0..90
  const int tid = threadIdx.x;
  const int wid = tid >> 6, lane = tid & 63, lg = lane >> 4, li = lane & 15;

  __shared__ ushort As[64 * 64];      // [r][k] bf16, swizzled rows (8KB)
  __shared__ ushort Bs[256 * 64];     // [n][k] bf16, swizzled rows (32KB)

  const int r0 = rt * 64;
  const int ar = tid >> 2, aseg = (tid & 3) * 16;
  const float* arow = rg + ((size_t)(r0 + ar) * T91 + tfix) * FDIM;

  f32x4 acc[4][4];
  #pragma unroll
  for (int a = 0; a < 4; ++a)
    #pragma unroll
    for (int b = 0; b < 4; ++b)
      #pragma unroll
      for (int i = 0; i < 4; ++i) acc[a][b][i] = 0.f;

  for (int ks = 0; ks < 4; ++ks) {
    const int k0 = ks * 64;
    float4 a0 = *(const float4*)&arow[k0 + aseg + 0];
    float4 a1 = *(const float4*)&arow[k0 + aseg + 4];
    float4 a2 = *(const float4*)&arow[k0 + aseg + 8];
    float4 a3 = *(const float4*)&arow[k0 + aseg + 12];
    short8v bv[8];                                   // FULL 128B row (was 4: half-staged -> NaN)
    #pragma unroll
    for (int j = 0; j < 8; ++j)
      bv[j] = *(const short8v*)&Wt[(size_t)tid * 256 + k0 + j * 8];
    __syncthreads();
    {
      const int sw = (ar & 7) << 4;
      const int ab = ar * 128 + (tid & 3) * 32;
      *(short8v*)((char*)As + ((ab + 0) ^ sw)) = pack8(a0, a1);
      *(short8v*)((char*)As + ((ab + 16) ^ sw)) = pack8(a2, a3);
      const int swb = (tid & 7) << 4;
      #pragma unroll
      for (int j = 0; j < 8; ++j)
        *(short8v*)((char*)Bs + (tid * 128 + ((j * 16) ^ swb))) = bv[j];
    }
    __syncthreads();
    #pragma unroll
    for (int kc = 0; kc < 2; ++kc) {
      short8v af[4], bfr[4];
      #pragma unroll
      for (int ms = 0; ms < 4; ++ms) {
        const int r = ms * 16 + li;
        af[ms] = *(const short8v*)((char*)As + ((r * 128 + kc * 64 + lg * 16) ^ ((r & 7) << 4)));
      }
      #pragma unroll
      for (int ns = 0; ns < 4; ++ns) {
        const int n = wid * 64 + ns * 16 + li;
        bfr[ns] = *(const short8v*)((char*)Bs + ((n * 128 + kc * 64 + lg * 16) ^ ((n & 7) << 4)));
      }
      #pragma unroll
      for (int ms = 0; ms < 4; ++ms)
        #pragma unroll
        for (int ns = 0; ns < 4; ++ns)
          acc[ms][ns] = __builtin_amdgcn_mfma_f32_16x16x32_bf16(af[ms], bfr[ns], acc[ms][ns], 0, 0, 0);
    }
  }

  const int th = tfix * HNUM + wid;
  float* kout = outKV + (size_t)th * RNUM * DDIM;
  #pragma unroll
  for (int ns = 0; ns < 4; ++ns) {
    const int d = ns * 16 + li;
    const float bb = bias[wid * 64 + d];
    #pragma unroll
    for (int ms = 0; ms < 4; ++ms) {
      float v[4];
      #pragma unroll
      for (int i = 0; i < 4; ++i) {
        v[i] = fmaxf(acc[ms][ns][i] + bb, 0.f);
        kout[(size_t)(r0 + ms * 16 + lg * 4 + i) * DDIM + d] = v[i];
      }
      if (ISV) {
        ushort4 u = {f2bf(v[0]), f2bf(v[1]), f2bf(v[2]), f2bf(v[3])};
        *(ushort4*)&Vt[((size_t)(th * 16 + rt) * 64 + d) * 64 + ms * 16 + lg * 4] = u;
      }
    }
  }
}

// ---------------------------------------------------------------------------
// Generic MFMA GEMM, BM=64 x BN=256, K=256.  MODE 0: Q (permute + q_scale),
// 1: Y2 (+agent residual), 2: F1 (relu -> bf16 out at col-offset).
// ---------------------------------------------------------------------------
template<int MODE>
__global__ __launch_bounds__(256) void mfma_gemm(
    const float* __restrict__ A, const ushort* __restrict__ Wt,
    const float* __restrict__ bias, float* __restrict__ out,
    const float* __restrict__ aux) {
  const int n0 = blockIdx.y * 64;
  const int m0 = blockIdx.x * 256;
  const int tid = threadIdx.x;
  const int wid = tid >> 6, lane = tid & 63, lg = lane >> 4, li = lane & 15;

  __shared__ ushort As[64 * 64];
  __shared__ ushort Bs[256 * 64];

  const int ar = tid >> 2, aseg = (tid & 3) * 16;
  const float* arow = A + (size_t)(n0 + ar) * 256;

  f32x4 acc[4][4];
  #pragma unroll
  for (int a = 0; a < 4; ++a)
    #pragma unroll
    for (int b = 0; b < 4; ++b)
      #pragma unroll
      for (int i = 0; i < 4; ++i) acc[a][b][i] = 0.f;

  for (int ks = 0; ks < 4; ++ks) {
    const int k0 = ks * 64;
    float4 a0 = *(const float4*)&arow[k0 + aseg + 0];
    float4 a1 = *(const float4*)&arow[k0 + aseg + 4];
    float4 a2 = *(const float4*)&arow[k0 + aseg + 8];
    float4 a3 = *(const float4*)&arow[k0 + aseg + 12];
    short8v bv[8];                                   // FULL 128B row (was 4: half-staged -> NaN)
    #pragma unroll
    for (int j = 0; j < 8; ++j)
      bv[j] = *(const short8v*)&Wt[(size_t)(m0 + tid) * 256 + k0 + j * 8];
    __syncthreads();
    {
      const int sw = (ar & 7) << 4;
      const int ab = ar * 128 + (tid & 3) * 32;
      *(short8v*)((char*)As + ((ab + 0) ^ sw)) = pack8(a0, a1);
      *(short8v*)((char*)As + ((ab + 16) ^ sw)) = pack8(a2, a3);
      const int swb = (tid & 7) << 4;
      #pragma unroll
      for (int j = 0; j < 8; ++j)
        *(short8v*)((char*)Bs + (tid * 128 + ((j * 16) ^ swb))) = bv[j];
    }
    __syncthreads();
    #pragma unroll
    for (int kc = 0; kc < 2; ++kc) {
      short8v af[4], bfr[4];
      #pragma unroll
      for (int ms = 0; ms < 4; ++ms) {
        const int r = ms * 16 + li;
        af[ms] = *(const short8v*)((char*)As + ((r * 128 + kc * 64 + lg * 16) ^ ((r & 7) << 4)));
      }
      #pragma unroll
      for (int ns = 0; ns < 4; ++ns) {
        const int n = wid * 64 + ns * 16 + li;
        bfr[ns] = *(const short8v*)((char*)Bs + ((n * 128 + kc * 64 + lg * 16) ^ ((n & 7) << 4)));
      }
      #pragma unroll
      for (int ms = 0; ms < 4; ++ms)
        #pragma unroll
        for (int ns = 0; ns < 4; ++ns)
          acc[ms][ns] = __builtin_amdgcn_mfma_f32_16x16x32_bf16(af[ms], bfr[ns], acc[ms][ns], 0, 0, 0);
    }
  }

  #pragma unroll
  for (int ns = 0; ns < 4; ++ns) {
    const int c = wid * 64 + ns * 16 + li;
    const float bb = bias[m0 + c];
    float qs = 0.f;
    if (MODE == 0) qs = aux[c & 63];
    #pragma unroll
    for (int ms = 0; ms < 4; ++ms) {
      #pragma unroll
      for (int i = 0; i < 4; ++i) {
        const int n = n0 + ms * 16 + lg * 4 + i;
        float v = fmaxf(acc[ms][ns][i] + bb, 0.f);
        if (MODE == 0) {            // Qh [T,H,A,D], n = a*91+t
          const int a = n / T91, t = n - a * T91;
          out[(((size_t)t * HNUM + (c >> 6)) * ANUM + a) * DDIM + (c & 63)] = v * qs;
        } else if (MODE == 1) {     // S = relu(Y2) + agent
          out[(size_t)n * FDIM + c] = v + aux[(size_t)n * FDIM + c];
        } else {                    // F1 bf16 [n][1024]
          ((ushort*)out)[(size_t)n * KFDIM + m0 + c] = f2bf(v);
        }
      }
    }
  }
}

// ---------------------------------------------------------------------------
// F2 = relu(F1b @ W_F2 + b) then LayerNorm -> Z.  512 thr, BM=64 x BN=256.
// ---------------------------------------------------------------------------
__global__ __launch_bounds__(512) void f2_ln_mfma(
    const ushort* __restrict__ F1b, const ushort* __restrict__ Wt,
    const float* __restrict__ b2, const float* __restrict__ g,
    const float* __restrict__ bb, float* __restrict__ Z) {
  const int n0 = blockIdx.x * 64;
  const int tid = threadIdx.x;
  const int wid = tid >> 6, lane = tid & 63, lg = lane >> 4, li = lane & 15;

  __shared__ ushort As[64 * 64];
  __shared__ ushort Bs[256 * 64];
  __shared__ float red[64][8][2];

  const int ar = tid >> 3, aseg = tid & 7;
  const int br = tid >> 1, bh = tid & 1;

  f32x4 acc[4][2];
  #pragma unroll
  for (int a = 0; a < 4; ++a)
    #pragma unroll
    for (int b = 0; b < 2; ++b)
      #pragma unroll
      for (int i = 0; i < 4; ++i) acc[a][b][i] = 0.f;

  for (int ks = 0; ks < 16; ++ks) {
    const int k0 = ks * 64;
    short8v av = *(const short8v*)&F1b[(size_t)(n0 + ar) * KFDIM + k0 + aseg * 8];
    short8v bv[4];
    #pragma unroll
    for (int j = 0; j < 4; ++j)
      bv[j] = *(const short8v*)&Wt[(size_t)br * KFDIM + k0 + bh * 32 + j * 8];
    __syncthreads();
    *(short8v*)((char*)As + (ar * 128 + ((aseg * 16) ^ ((ar & 7) << 4)))) = av;
    #pragma unroll
    for (int j = 0; j < 4; ++j)
      *(short8v*)((char*)Bs + (br * 128 + ((bh * 64 + j * 16) ^ ((br & 7) << 4)))) = bv[j];
    __syncthreads();
    #pragma unroll
    for (int kc = 0; kc < 2; ++kc) {
      short8v af[4], bfr[2];
      #pragma unroll
      for (int ms = 0; ms < 4; ++ms) {
        const int r = ms * 16 + li;
        af[ms] = *(const short8v*)((char*)As + ((r * 128 + kc * 64 + lg * 16) ^ ((r & 7) << 4)));
      }
      #pragma unroll
      for (int ns = 0; ns < 2; ++ns) {
        const int n = wid * 32 + ns * 16 + li;
        bfr[ns] = *(const short8v*)((char*)Bs + ((n * 128 + kc * 64 + lg * 16) ^ ((n & 7) << 4)));
      }
      #pragma unroll
      for (int ms = 0; ms < 4; ++ms)
        #pragma unroll
        for (int ns = 0; ns < 2; ++ns)
          acc[ms][ns] = __builtin_amdgcn_mfma_f32_16x16x32_bf16(af[ms], bfr[ns], acc[ms][ns], 0, 0, 0);
    }
  }

  #pragma unroll
  for (int ms = 0; ms < 4; ++ms) {
    #pragma unroll
    for (int i = 0; i < 4; ++i) {
      float s = 0.f, sq = 0.f;
      #pragma unroll
      for (int ns = 0; ns < 2; ++ns) {
        const float b = b2[wid * 32 + ns * 16 + li];
        float v = fmaxf(acc[ms][ns][i] + b, 0.f);
        acc[ms][ns][i] = v;
        s += v; sq += v * v;
      }
      s += __shfl_xor(s, 1); sq += __shfl_xor(sq, 1);
      s += __shfl_xor(s, 2); sq += __shfl_xor(sq, 2);
      s += __shfl_xor(s, 4); sq += __shfl_xor(sq, 4);
      s += __shfl_xor(s, 8); sq += __shfl_xor(sq, 8);
      if (li == 0) {
        const int r = ms * 16 + lg * 4 + i;
        red[r][wid][0] = s; red[r][wid][1] = sq;
      }
    }
  }
  __syncthreads();

  const float g0 = g[wid * 32 + li],       g1 = g[wid * 32 + 16 + li];
  const float e0 = bb[wid * 32 + li],      e1 = bb[wid * 32 + 16 + li];
  #pragma unroll
  for (int ms = 0; ms < 4; ++ms) {
    #pragma unroll
    for (int i = 0; i < 4; ++i) {
      const int r = ms * 16 + lg * 4 + i;
      float s = 0.f, sq = 0.f;
      #pragma unroll
      for (int w = 0; w < 8; ++w) { s += red[r][w][0]; sq += red[r][w][1]; }
      const float mu = s * (1.f / 256.f);
      const float var = sq * (1.f / 256.f) - mu * mu;
      const float rs = rsqrtf(var + 1e-5f);
      float* zp = Z + (size_t)(n0 + r) * FDIM;
      zp[wid * 32 + li]      = (acc[ms][0][i] - mu) * rs * g0 + e0;
      zp[wid * 32 + 16 + li] = (acc[ms][1][i] - mu) * rs * g1 + e1;
    }
  }
}

// ---------------------------------------------------------------------------
// MFMA flash attention stage 1 (V^T tile-blocked bf16).
// ---------------------------------------------------------------------------
__global__ __launch_bounds__(256) void attn_mfma(
    const float* __restrict__ Qh, const float* __restrict__ Kh,
    const ushort* __restrict__ Vt, float* __restrict__ Pacc,
    float* __restrict__ Pml) {
  const int th = blockIdx.x, g = blockIdx.y;
  const int tid = threadIdx.x;
  const int wid = tid >> 6, lane = tid & 63;
  const int lg = lane >> 4, li = lane & 15;

  __shared__ ushort Kl[4096];
  __shared__ ushort Vl[4096];
  __shared__ ushort Pl[8192];

  short8v qf[2][2];
  #pragma unroll
  for (int qsub = 0; qsub < 2; ++qsub)
    #pragma unroll
    for (int kc = 0; kc < 2; ++kc) {
      const float* qp = Qh + ((size_t)th * ANUM + wid * 32 + qsub * 16 + li) * DDIM + kc * 32 + lg * 8;
      float4 x = *(const float4*)qp;
      float4 y = *(const float4*)(qp + 4);
      qf[qsub][kc] = pack8(make_float4(x.x*0.5f, x.y*0.5f, x.z*0.5f, x.w*0.5f),
                           make_float4(y.x*0.5f, y.y*0.5f, y.z*0.5f, y.w*0.5f));
    }

  f32x4 yacc[2][4];
  #pragma unroll
  for (int a = 0; a < 2; ++a)
    #pragma unroll
    for (int b = 0; b < 4; ++b)
      #pragma unroll
      for (int i = 0; i < 4; ++i) yacc[a][b][i] = 0.f;

  float mrow[2][4], lrow[2][4];
  #pragma unroll
  for (int a = 0; a < 2; ++a)
    #pragma unroll
    for (int i = 0; i < 4; ++i) { mrow[a][i] = -1e30f; lrow[a][i] = 0.f; }

  const float*  Kb = Kh + (size_t)th * RNUM * DDIM;
  const ushort* Vb = Vt + (size_t)th * 16 * 4096;

  const int krr = wid * 16 + (lane >> 2);
  const int kd0 = (lane & 3) * 16;

  for (int tt = 0; tt < 8; ++tt) {
    const int r0 = g * 512 + tt * 64;
    const int rt = g * 8 + tt;
    __syncthreads();
    {
      const float* kp = Kb + (size_t)(r0 + krr) * DDIM + kd0;
      float4 a = *(const float4*)kp,       b = *(const float4*)(kp + 4),
             c = *(const float4*)(kp + 8), d = *(const float4*)(kp + 12);
      const int base = krr * 128 + kd0 * 2;
      const int sw = (krr & 7) << 4;
      *(short8v*)((char*)Kl + (base ^ sw)) = pack8(a, b);
      *(short8v*)((char*)Kl + ((base + 16) ^ sw)) = pack8(c, d);
    }
    const ushort* vtile = Vb + rt * 4096;
    #pragma unroll
    for (int c = 0; c < 2; ++c) {
      const int B = (wid * 2 + c) * 1024 + lane * 16;
      const int sw = ((B >> 7) & 7) << 4;
      short8v v = *(const short8v*)((const char*)vtile + (B ^ sw));
      *(short8v*)((char*)Vl + B) = v;
    }
    __syncthreads();

    f32x4 sf[2][4];
    #pragma unroll
    for (int a = 0; a < 2; ++a)
      #pragma unroll
      for (int b = 0; b < 4; ++b)
        #pragma unroll
        for (int i = 0; i < 4; ++i) sf[a][b][i] = 0.f;

    #pragma unroll
    for (int kc = 0; kc < 2; ++kc) {
      short8v kf[4];
      #pragma unroll
      for (int rsub = 0; rsub < 4; ++rsub) {
        const int rl = rsub * 16 + li;
        kf[rsub] = *(const short8v*)((char*)Kl + ((rl * 128 + kc * 64 + lg * 16) ^ ((rl & 7) << 4)));
      }
      #pragma unroll
      for (int qsub = 0; qsub < 2; ++qsub)
        #pragma unroll
        for (int rsub = 0; rsub < 4; ++rsub)
          sf[qsub][rsub] = __builtin_amdgcn_mfma_f32_16x16x32_bf16(
              qf[qsub][kc], kf[rsub], sf[qsub][rsub], 0, 0, 0);
    }

    #pragma unroll
    for (int qsub = 0; qsub < 2; ++qsub)
      #pragma unroll
      for (int i = 0; i < 4; ++i) {
        float em = fmaxf(fmaxf(sf[qsub][0][i], sf[qsub][1][i]),
                         fmaxf(sf[qsub][2][i], sf[qsub][3][i]));
        em = fmaxf(em, __shfl_xor(em, 1));
        em = fmaxf(em, __shfl_xor(em, 2));
        em = fmaxf(em, __shfl_xor(em, 4));
        em = fmaxf(em, __shfl_xor(em, 8));
        const float mn = fmaxf(mrow[qsub][i], em);
        const float fs = __expf(mrow[qsub][i] - mn);
        mrow[qsub][i] = mn;
        const float p0 = __expf(sf[qsub][0][i] - mn);
        const float p1 = __expf(sf[qsub][1][i] - mn);
        const float p2 = __expf(sf[qsub][2][i] - mn);
        const float p3 = __expf(sf[qsub][3][i] - mn);
        float rs = p0 + p1 + p2 + p3;
        rs += __shfl_xor(rs, 1);
        rs += __shfl_xor(rs, 2);
        rs += __shfl_xor(rs, 4);
        rs += __shfl_xor(rs, 8);
        lrow[qsub][i] = lrow[qsub][i] * fs + rs;
        #pragma unroll
        for (int dsub = 0; dsub < 4; ++dsub) yacc[qsub][dsub][i] *= fs;
        const int q = qsub * 16 + lg * 4 + i;
        const int sw = (q & 7) << 4;
        char* pb = (char*)Pl + wid * 4096;
        *(ushort*)(pb + ((q * 128 + (0 * 16 + li) * 2) ^ sw)) = f2bf(p0);
        *(ushort*)(pb + ((q * 128 + (1 * 16 + li) * 2) ^ sw)) = f2bf(p1);
        *(ushort*)(pb + ((q * 128 + (2 * 16 + li) * 2) ^ sw)) = f2bf(p2);
        *(ushort*)(pb + ((q * 128 + (3 * 16 + li) * 2) ^ sw)) = f2bf(p3);
      }

    #pragma unroll
    for (int rc = 0; rc < 2; ++rc) {
      short8v pa[2];
      #pragma unroll
      for (int qsub = 0; qsub < 2; ++qsub) {
        const int qq = qsub * 16 + li;
        pa[qsub] = *(const short8v*)((char*)Pl + wid * 4096 +
                    ((qq * 128 + rc * 64 + lg * 16) ^ ((qq & 7) << 4)));
      }
      #pragma unroll
      for (int dsub = 0; dsub < 4; ++dsub) {
        const int dd = dsub * 16 + li;
        short8v vb = *(const short8v*)((char*)Vl +
                      ((dd * 128 + rc * 64 + lg * 16) ^ ((dd & 7) << 4)));
        #pragma unroll
        for (int qsub = 0; qsub < 2; ++qsub)
          yacc[qsub][dsub] = __builtin_amdgcn_mfma_f32_16x16x32_bf16(
              pa[qsub], vb, yacc[qsub][dsub], 0, 0, 0);
      }
    }
  }

  const int thg = th * 2 + g;
  float* pp = Pacc + (size_t)thg * 8192;
  #pragma unroll
  for (int qsub = 0; qsub < 2; ++qsub)
    #pragma unroll
    for (int dsub = 0; dsub < 4; ++dsub)
      #pragma unroll
      for (int i = 0; i < 4; ++i) {
        const int q = wid * 32 + qsub * 16 + lg * 4 + i;
        pp[q * 64 + dsub * 16 + li] = yacc[qsub][dsub][i];
      }
  if (li == 0) {
    #pragma unroll
    for (int qsub = 0; qsub < 2; ++qsub)
      #pragma unroll
      for (int i = 0; i < 4; ++i) {
        const int q = wid * 32 + qsub * 16 + lg * 4 + i;
        Pml[(size_t)thg * 256 + q] = mrow[qsub][i];
        Pml[(size_t)thg * 256 + 128 + q] = lrow[qsub][i];
      }
  }
}

__global__ __launch_bounds__(128) void attn_combine(
    const float* __restrict__ Pacc, const float* __restrict__ Pml,
    float* __restrict__ Y1) {
  const int th = blockIdx.x;
  const int t = th >> 2, h = th & 3;
  const int a = threadIdx.x;
  const float m0 = Pml[(size_t)(th * 2 + 0) * 256 + a];
  const float l0 = Pml[(size_t)(th * 2 + 0) * 256 + 128 + a];
  const float m1 = Pml[(size_t)(th * 2 + 1) * 256 + a];
  const float l1 = Pml[(size_t)(th * 2 + 1) * 256 + 128 + a];
  const float mn = fmaxf(m0, m1);
  const float s0 = __expf(m0 - mn), s1 = __expf(m1 - mn);
  const float inv = 1.f / (s0 * l0 + s1 * l1);
  const float* p0 = Pacc + (size_t)(th * 2 + 0) * 8192 + a * 64;
  const float* p1 = Pacc + (size_t)(th * 2 + 1) * 8192 + a * 64;
  float* yp = Y1 + ((size_t)a * T91 + t) * FDIM + h * DDIM;
  #pragma unroll
  for (int i = 0; i < 16; ++i) {
    float4 v0 = *(const float4*)(p0 + i * 4);
    float4 v1 = *(const float4*)(p1 + i * 4);
    float4 o = {(s0 * v0.x + s1 * v1.x) * inv, (s0 * v0.y + s1 * v1.y) * inv,
                (s0 * v0.z + s1 * v1.z) * inv, (s0 * v0.w + s1 * v1.w) * inv};
    *(float4*)(yp + i * 4) = o;
  }
}

// ---------------------------------------------------------------------------
extern "C" void kernel_launch(void* const* d_in, const int* in_sizes, int n_in,
                              void* d_out, int out_size, void* d_ws, size_t ws_size,
                              hipStream_t stream) {
  (void)in_sizes; (void)n_in; (void)out_size; (void)ws_size;

  const float* agent   = (const float*)d_in[0];
  const float* rg      = (const float*)d_in[1];
  const float* W_K     = (const float*)d_in[2];
  const float* b_K     = (const float*)d_in[3];
  const float* W_V     = (const float*)d_in[4];
  const float* b_V     = (const float*)d_in[5];
  const float* W_Q     = (const float*)d_in[6];
  const float* b_Q     = (const float*)d_in[7];
  const float* q_scale = (const float*)d_in[8];
  const float* W_Y2    = (const float*)d_in[9];
  const float* b_Y2    = (const float*)d_in[10];
  const float* W_F1    = (const float*)d_in[11];
  const float* b_F1    = (const float*)d_in[12];
  const float* W_F2    = (const float*)d_in[13];
  const float* b_F2    = (const float*)d_in[14];
  const float* ln_g    = (const float*)d_in[15];
  const float* ln_b    = (const float*)d_in[16];

  float* out = (float*)d_out;
  float* Z  = out;                       // [A,T,F]
  float* Qh = out + 2981888;             // [T,H,A,D]
  float* Kh = out + 5963776;             // [T,H,R,D]
  float* Vh = out + 29818880;            // [T,H,R,D]

  // workspace (85.1 MB):
  char* w = (char*)d_ws;
  ushort* WKt  = (ushort*)w;                    w += 65536 * 2;
  ushort* WVt  = (ushort*)w;                    w += 65536 * 2;
  ushort* WQt  = (ushort*)w;                    w += 65536 * 2;
  ushort* WY2t = (ushort*)w;                    w += 65536 * 2;
  ushort* WF1t = (ushort*)w;                    w += 262144 * 2;
  ushort* WF2t = (ushort*)w;                    w += 262144 * 2;
  float*  S    = (float*)w;                     w += (size_t)11648 * 256 * 4;
  ushort* F1b  = (ushort*)w;                    w += (size_t)11648 * 1024 * 2;
  ushort* Vt   = (ushort*)w;                    // 23,855,104 ushort
  float*  Y1   = (float*)Vt;                    // alias: Vt dead after attn
  float*  Pacc = (float*)F1b;                   // 728*8192*4 B == F1b size
  float*  Pml  = S;                             // 745 KB <= S

  const dim3 blk(256);

  // weight transpose+convert (bf16 W^T)
  wconv<<<dim3(256), blk, 0, stream>>>(W_K,  WKt,  256, 256, 65536);
  wconv<<<dim3(256), blk, 0, stream>>>(W_V,  WVt,  256, 256, 65536);
  wconv<<<dim3(256), blk, 0, stream>>>(W_Q,  WQt,  256, 256, 65536);
  wconv<<<dim3(256), blk, 0, stream>>>(W_Y2, WY2t, 256, 256, 65536);
  wconv<<<dim3(1024), blk, 0, stream>>>(W_F1, WF1t, 256, 1024, 262144);
  wconv<<<dim3(1024), blk, 0, stream>>>(W_F2, WF2t, 1024, 256, 262144);

  // K/V projections (MFMA), fixed-t blocks
  kvproj_mfma<0><<<dim3(16, 91), blk, 0, stream>>>(rg, WKt, b_K, Kh, nullptr);
  kvproj_mfma<1><<<dim3(16, 91), blk, 0, stream>>>(rg, WVt, b_V, Vh, Vt);
  // Q projection
  mfma_gemm<0><<<dim3(1, 182), blk, 0, stream>>>(agent, WQt, b_Q, Qh, q_scale);

  // attention
  attn_mfma<<<dim3(364, 2), blk, 0, stream>>>(Qh, Kh, Vt, Pacc, Pml);
  attn_combine<<<dim3(364), dim3(128), 0, stream>>>(Pacc, Pml, Y1);

  // Y2 + residual -> S ; F1 -> bf16 ; F2+LN -> Z
  mfma_gemm<1><<<dim3(1, 182), blk, 0, stream>>>(Y1, WY2t, b_Y2, S, agent);
  mfma_gemm<2><<<dim3(4, 182), blk, 0, stream>>>(S, WF1t, b_F1, (float*)F1b, nullptr);
  f2_ln_mfma<<<dim3(182), dim3(512), 0, stream>>>(F1b, WF2t, b_F2, ln_g, ln_b, Z);
}

// Round 6
// 524.346 us; speedup vs baseline: 3.5091x; 1.0624x over previous
//
#include <hip/hip_runtime.h>

#define T91  91
#define FDIM 256
#define HNUM 4
#define DDIM 64
#define ANUM 128
#define RNUM 1024
#define KFDIM 1024

typedef __attribute__((ext_vector_type(8))) short short8v;
typedef __attribute__((ext_vector_type(4))) float f32x4;

__device__ __forceinline__ ushort f2bf(float f) {
  union { float f; uint32_t u; } c; c.f = f;
  return (ushort)((c.u + 0x7FFFu + ((c.u >> 16) & 1u)) >> 16);
}
__device__ __forceinline__ short8v pack8(float4 a, float4 b) {
  short8v v;
  v[0] = (short)f2bf(a.x); v[1] = (short)f2bf(a.y);
  v[2] = (short)f2bf(a.z); v[3] = (short)f2bf(a.w);
  v[4] = (short)f2bf(b.x); v[5] = (short)f2bf(b.y);
  v[6] = (short)f2bf(b.z); v[7] = (short)f2bf(b.w);
  return v;
}
__device__ __forceinline__ uint32_t cvtpk(float lo, float hi) {
  uint32_t r;
  asm("v_cvt_pk_bf16_f32 %0, %1, %2" : "=v"(r) : "v"(lo), "v"(hi));
  return r;
}

// ---------------------------------------------------------------------------
// All weight transposes+converts in ONE kernel.  Wt[m][k] = bf16(W[k][m]).
// ---------------------------------------------------------------------------
__global__ __launch_bounds__(256) void wconv_all(
    const float* __restrict__ W_K, const float* __restrict__ W_V,
    const float* __restrict__ W_Q, const float* __restrict__ W_Y2,
    const float* __restrict__ W_F1, const float* __restrict__ W_F2,
    ushort* __restrict__ WKt, ushort* __restrict__ WVt,
    ushort* __restrict__ WQt, ushort* __restrict__ WY2t,
    ushort* __restrict__ WF1t, ushort* __restrict__ WF2t) {
  const int b = blockIdx.x, tid = threadIdx.x;
  const float* W; ushort* Wt; int Kd, Md, o;
  if (b < 1024) {
    const int s = b >> 8;
    W  = (s == 0) ? W_K : (s == 1) ? W_V : (s == 2) ? W_Q : W_Y2;
    Wt = (s == 0) ? WKt : (s == 1) ? WVt : (s == 2) ? WQt : WY2t;
    Kd = 256; Md = 256; o = (b & 255) * 256 + tid;
  } else if (b < 2048) {
    W = W_F1; Wt = WF1t; Kd = 256; Md = 1024; o = (b - 1024) * 256 + tid;
  } else {
    W = W_F2; Wt = WF2t; Kd = 1024; Md = 256; o = (b - 2048) * 256 + tid;
  }
  const int m = o / Kd, k = o - m * Kd;
  Wt[o] = f2bf(W[(size_t)k * Md + m]);
}

// ---------------------------------------------------------------------------
// Fused K+V projection, MFMA.  Block = fixed t, 64 r-rows, 512 threads.
// Waves 0-3: K cols h=wid; waves 4-7: V cols h=wid-4.  rg read ONCE.
// Out: fp32 [T,H,R,D] for both; bf16 V^T tiles Vt[th][rt][d 64][r 64].
// ---------------------------------------------------------------------------
__global__ __launch_bounds__(512) void kvproj_fused(
    const float* __restrict__ rg, const ushort* __restrict__ WKt,
    const ushort* __restrict__ WVt, const float* __restrict__ b_K,
    const float* __restrict__ b_V, float* __restrict__ Kh,
    float* __restrict__ Vh, ushort* __restrict__ Vt) {
  const int rt = blockIdx.x;          // 0..15
  const int tfix = blockIdx.y;        // 0..90
  const int tid = threadIdx.x;
  const int wid = tid >> 6, lane = tid & 63, lg = lane >> 4, li = lane & 15;

  __shared__ ushort As[64 * 64];      // [r][k] swizzled (8KB)
  __shared__ ushort Bs[512 * 64];     // [n][k] swizzled (64KB): 256 K + 256 V

  const int r0 = rt * 64;
  const int ar = tid >> 3, aseg = (tid & 7) * 8;     // 8 thr/row, 8 f32 each
  const float* arow = rg + ((size_t)(r0 + ar) * T91 + tfix) * FDIM;
  const ushort* brow = (tid < 256) ? (WKt + (size_t)tid * 256)
                                   : (WVt + (size_t)(tid - 256) * 256);

  f32x4 acc[4][4];
  #pragma unroll
  for (int a = 0; a < 4; ++a)
    #pragma unroll
    for (int b = 0; b < 4; ++b)
      #pragma unroll
      for (int i = 0; i < 4; ++i) acc[a][b][i] = 0.f;

  for (int ks = 0; ks < 4; ++ks) {
    const int k0 = ks * 64;
    float4 a0 = *(const float4*)&arow[k0 + aseg + 0];
    float4 a1 = *(const float4*)&arow[k0 + aseg + 4];
    short8v bv[8];
    #pragma unroll
    for (int j = 0; j < 8; ++j)
      bv[j] = *(const short8v*)&brow[k0 + j * 8];
    __syncthreads();
    {
      const int sw = (ar & 7) << 4;
      *(short8v*)((char*)As + (ar * 128 + (((tid & 7) * 16) ^ sw))) = pack8(a0, a1);
      const int swb = (tid & 7) << 4;
      #pragma unroll
      for (int j = 0; j < 8; ++j)
        *(short8v*)((char*)Bs + (tid * 128 + ((j * 16) ^ swb))) = bv[j];
    }
    __syncthreads();
    #pragma unroll
    for (int kc = 0; kc < 2; ++kc) {
      short8v af[4], bfr[4];
      #pragma unroll
      for (int ms = 0; ms < 4; ++ms) {
        const int r = ms * 16 + li;
        af[ms] = *(const short8v*)((char*)As + ((r * 128 + kc * 64 + lg * 16) ^ ((r & 7) << 4)));
      }
      #pragma unroll
      for (int ns = 0; ns < 4; ++ns) {
        const int n = wid * 64 + ns * 16 + li;     // wid>=4 lands in V half
        bfr[ns] = *(const short8v*)((char*)Bs + ((n * 128 + kc * 64 + lg * 16) ^ ((n & 7) << 4)));
      }
      #pragma unroll
      for (int ms = 0; ms < 4; ++ms)
        #pragma unroll
        for (int ns = 0; ns < 4; ++ns)
          acc[ms][ns] = __builtin_amdgcn_mfma_f32_16x16x32_bf16(af[ms], bfr[ns], acc[ms][ns], 0, 0, 0);
    }
  }

  const int hsel = wid & 3;
  const int th = tfix * HNUM + hsel;
  const bool isv = wid >= 4;
  const float* bias = isv ? b_V : b_K;
  float* kout = (isv ? Vh : Kh) + (size_t)th * RNUM * DDIM;
  #pragma unroll
  for (int ns = 0; ns < 4; ++ns) {
    const int d = ns * 16 + li;
    const float bb = bias[hsel * 64 + d];
    #pragma unroll
    for (int ms = 0; ms < 4; ++ms) {
      float v[4];
      #pragma unroll
      for (int i = 0; i < 4; ++i) {
        v[i] = fmaxf(acc[ms][ns][i] + bb, 0.f);
        kout[(size_t)(r0 + ms * 16 + lg * 4 + i) * DDIM + d] = v[i];
      }
      if (isv) {
        ushort4 u = {f2bf(v[0]), f2bf(v[1]), f2bf(v[2]), f2bf(v[3])};
        *(ushort4*)&Vt[((size_t)(th * 16 + rt) * 64 + d) * 64 + ms * 16 + lg * 4] = u;
      }
    }
  }
}

// ---------------------------------------------------------------------------
// Generic MFMA GEMM, BM=64 x BN=256, K=256.  MODE 0: Q (permute + q_scale),
// MODE 2: F1 (relu -> bf16 out at col-offset m0).
// ---------------------------------------------------------------------------
template<int MODE>
__global__ __launch_bounds__(256) void mfma_gemm(
    const float* __restrict__ A, const ushort* __restrict__ Wt,
    const float* __restrict__ bias, float* __restrict__ out,
    const float* __restrict__ aux) {
  const int n0 = blockIdx.y * 64;
  const int m0 = blockIdx.x * 256;
  const int tid = threadIdx.x;
  const int wid = tid >> 6, lane = tid & 63, lg = lane >> 4, li = lane & 15;

  __shared__ ushort As[64 * 64];
  __shared__ ushort Bs[256 * 64];

  const int ar = tid >> 2, aseg = (tid & 3) * 16;
  const float* arow = A + (size_t)(n0 + ar) * 256;

  f32x4 acc[4][4];
  #pragma unroll
  for (int a = 0; a < 4; ++a)
    #pragma unroll
    for (int b = 0; b < 4; ++b)
      #pragma unroll
      for (int i = 0; i < 4; ++i) acc[a][b][i] = 0.f;

  for (int ks = 0; ks < 4; ++ks) {
    const int k0 = ks * 64;
    float4 a0 = *(const float4*)&arow[k0 + aseg + 0];
    float4 a1 = *(const float4*)&arow[k0 + aseg + 4];
    float4 a2 = *(const float4*)&arow[k0 + aseg + 8];
    float4 a3 = *(const float4*)&arow[k0 + aseg + 12];
    short8v bv[8];
    #pragma unroll
    for (int j = 0; j < 8; ++j)
      bv[j] = *(const short8v*)&Wt[(size_t)(m0 + tid) * 256 + k0 + j * 8];
    __syncthreads();
    {
      const int sw = (ar & 7) << 4;
      const int ab = ar * 128 + (tid & 3) * 32;
      *(short8v*)((char*)As + ((ab + 0) ^ sw)) = pack8(a0, a1);
      *(short8v*)((char*)As + ((ab + 16) ^ sw)) = pack8(a2, a3);
      const int swb = (tid & 7) << 4;
      #pragma unroll
      for (int j = 0; j < 8; ++j)
        *(short8v*)((char*)Bs + (tid * 128 + ((j * 16) ^ swb))) = bv[j];
    }
    __syncthreads();
    #pragma unroll
    for (int kc = 0; kc < 2; ++kc) {
      short8v af[4], bfr[4];
      #pragma unroll
      for (int ms = 0; ms < 4; ++ms) {
        const int r = ms * 16 + li;
        af[ms] = *(const short8v*)((char*)As + ((r * 128 + kc * 64 + lg * 16) ^ ((r & 7) << 4)));
      }
      #pragma unroll
      for (int ns = 0; ns < 4; ++ns) {
        const int n = wid * 64 + ns * 16 + li;
        bfr[ns] = *(const short8v*)((char*)Bs + ((n * 128 + kc * 64 + lg * 16) ^ ((n & 7) << 4)));
      }
      #pragma unroll
      for (int ms = 0; ms < 4; ++ms)
        #pragma unroll
        for (int ns = 0; ns < 4; ++ns)
          acc[ms][ns] = __builtin_amdgcn_mfma_f32_16x16x32_bf16(af[ms], bfr[ns], acc[ms][ns], 0, 0, 0);
    }
  }

  #pragma unroll
  for (int ns = 0; ns < 4; ++ns) {
    const int c = wid * 64 + ns * 16 + li;
    const float bb = bias[m0 + c];
    float qs = 0.f;
    if (MODE == 0) qs = aux[c & 63];
    #pragma unroll
    for (int ms = 0; ms < 4; ++ms) {
      #pragma unroll
      for (int i = 0; i < 4; ++i) {
        const int n = n0 + ms * 16 + lg * 4 + i;
        float v = fmaxf(acc[ms][ns][i] + bb, 0.f);
        if (MODE == 0) {            // Qh [T,H,A,D], n = a*91+t
          const int a = n / T91, t = n - a * T91;
          out[(((size_t)t * HNUM + (c >> 6)) * ANUM + a) * DDIM + (c & 63)] = v * qs;
        } else {                    // F1 bf16 [n][1024]
          ((ushort*)out)[(size_t)n * KFDIM + m0 + c] = f2bf(v);
        }
      }
    }
  }
}

// ---------------------------------------------------------------------------
// Y2 GEMM with fused attention-combine A-staging.
// A row n = a*91+t; per ks (=h): A[n][ks*64+d] = (s0*Pacc0 + s1*Pacc1)*inv.
// Out: S = relu(Y2+b) + agent.
// ---------------------------------------------------------------------------
__global__ __launch_bounds__(256) void y2_gemm(
    const float* __restrict__ Pacc, const float* __restrict__ Pml,
    const ushort* __restrict__ Wt, const float* __restrict__ bias,
    float* __restrict__ S, const float* __restrict__ agent) {
  const int n0 = blockIdx.x * 64;
  const int tid = threadIdx.x;
  const int wid = tid >> 6, lane = tid & 63, lg = lane >> 4, li = lane & 15;

  __shared__ ushort As[64 * 64];
  __shared__ ushort Bs[256 * 64];

  const int ar = tid >> 2, aseg = (tid & 3) * 16;
  const int n = n0 + ar;
  const int a = n / T91, t = n - a * T91;

  f32x4 acc[4][4];
  #pragma unroll
  for (int q = 0; q < 4; ++q)
    #pragma unroll
    for (int b = 0; b < 4; ++b)
      #pragma unroll
      for (int i = 0; i < 4; ++i) acc[q][b][i] = 0.f;

  for (int ks = 0; ks < 4; ++ks) {
    const int k0 = ks * 64;
    const int th = t * 4 + ks;
    const float m0v = Pml[(size_t)(th * 2 + 0) * 256 + a];
    const float l0v = Pml[(size_t)(th * 2 + 0) * 256 + 128 + a];
    const float m1v = Pml[(size_t)(th * 2 + 1) * 256 + a];
    const float l1v = Pml[(size_t)(th * 2 + 1) * 256 + 128 + a];
    const float mn = fmaxf(m0v, m1v);
    const float s0 = __expf(m0v - mn), s1 = __expf(m1v - mn);
    const float inv = 1.f / (s0 * l0v + s1 * l1v);
    const float* p0 = Pacc + (size_t)(th * 2 + 0) * 8192 + a * 64 + aseg;
    const float* p1 = Pacc + (size_t)(th * 2 + 1) * 8192 + a * 64 + aseg;
    float4 x[4];
    #pragma unroll
    for (int j = 0; j < 4; ++j) {
      float4 u = *(const float4*)(p0 + j * 4);
      float4 v = *(const float4*)(p1 + j * 4);
      x[j] = make_float4((s0 * u.x + s1 * v.x) * inv, (s0 * u.y + s1 * v.y) * inv,
                         (s0 * u.z + s1 * v.z) * inv, (s0 * u.w + s1 * v.w) * inv);
    }
    short8v bv[8];
    #pragma unroll
    for (int j = 0; j < 8; ++j)
      bv[j] = *(const short8v*)&Wt[(size_t)tid * 256 + k0 + j * 8];
    __syncthreads();
    {
      const int sw = (ar & 7) << 4;
      const int ab = ar * 128 + (tid & 3) * 32;
      *(short8v*)((char*)As + ((ab + 0) ^ sw)) = pack8(x[0], x[1]);
      *(short8v*)((char*)As + ((ab + 16) ^ sw)) = pack8(x[2], x[3]);
      const int swb = (tid & 7) << 4;
      #pragma unroll
      for (int j = 0; j < 8; ++j)
        *(short8v*)((char*)Bs + (tid * 128 + ((j * 16) ^ swb))) = bv[j];
    }
    __syncthreads();
    #pragma unroll
    for (int kc = 0; kc < 2; ++kc) {
      short8v af[4], bfr[4];
      #pragma unroll
      for (int ms = 0; ms < 4; ++ms) {
        const int r = ms * 16 + li;
        af[ms] = *(const short8v*)((char*)As + ((r * 128 + kc * 64 + lg * 16) ^ ((r & 7) << 4)));
      }
      #pragma unroll
      for (int ns = 0; ns < 4; ++ns) {
        const int nn = wid * 64 + ns * 16 + li;
        bfr[ns] = *(const short8v*)((char*)Bs + ((nn * 128 + kc * 64 + lg * 16) ^ ((nn & 7) << 4)));
      }
      #pragma unroll
      for (int ms = 0; ms < 4; ++ms)
        #pragma unroll
        for (int ns = 0; ns < 4; ++ns)
          acc[ms][ns] = __builtin_amdgcn_mfma_f32_16x16x32_bf16(af[ms], bfr[ns], acc[ms][ns], 0, 0, 0);
    }
  }

  #pragma unroll
  for (int ns = 0; ns < 4; ++ns) {
    const int c = wid * 64 + ns * 16 + li;
    const float bb = bias[c];
    #pragma unroll
    for (int ms = 0; ms < 4; ++ms) {
      #pragma unroll
      for (int i = 0; i < 4; ++i) {
        const int nn = n0 + ms * 16 + lg * 4 + i;
        float v = fmaxf(acc[ms][ns][i] + bb, 0.f);
        S[(size_t)nn * FDIM + c] = v + agent[(size_t)nn * FDIM + c];
      }
    }
  }
}

// ---------------------------------------------------------------------------
// F2 = relu(F1b @ W_F2 + b) then LayerNorm -> Z.  512 thr, BM=64 x BN=256.
// ---------------------------------------------------------------------------
__global__ __launch_bounds__(512) void f2_ln_mfma(
    const ushort* __restrict__ F1b, const ushort* __restrict__ Wt,
    const float* __restrict__ b2, const float* __restrict__ g,
    const float* __restrict__ bb, float* __restrict__ Z) {
  const int n0 = blockIdx.x * 64;
  const int tid = threadIdx.x;
  const int wid = tid >> 6, lane = tid & 63, lg = lane >> 4, li = lane & 15;

  __shared__ ushort As[64 * 64];
  __shared__ ushort Bs[256 * 64];
  __shared__ float red[64][8][2];

  const int ar = tid >> 3, aseg = tid & 7;
  const int br = tid >> 1, bh = tid & 1;

  f32x4 acc[4][2];
  #pragma unroll
  for (int a = 0; a < 4; ++a)
    #pragma unroll
    for (int b = 0; b < 2; ++b)
      #pragma unroll
      for (int i = 0; i < 4; ++i) acc[a][b][i] = 0.f;

  for (int ks = 0; ks < 16; ++ks) {
    const int k0 = ks * 64;
    short8v av = *(const short8v*)&F1b[(size_t)(n0 + ar) * KFDIM + k0 + aseg * 8];
    short8v bv[4];
    #pragma unroll
    for (int j = 0; j < 4; ++j)
      bv[j] = *(const short8v*)&Wt[(size_t)br * KFDIM + k0 + bh * 32 + j * 8];
    __syncthreads();
    *(short8v*)((char*)As + (ar * 128 + ((aseg * 16) ^ ((ar & 7) << 4)))) = av;
    #pragma unroll
    for (int j = 0; j < 4; ++j)
      *(short8v*)((char*)Bs + (br * 128 + ((bh * 64 + j * 16) ^ ((br & 7) << 4)))) = bv[j];
    __syncthreads();
    #pragma unroll
    for (int kc = 0; kc < 2; ++kc) {
      short8v af[4], bfr[2];
      #pragma unroll
      for (int ms = 0; ms < 4; ++ms) {
        const int r = ms * 16 + li;
        af[ms] = *(const short8v*)((char*)As + ((r * 128 + kc * 64 + lg * 16) ^ ((r & 7) << 4)));
      }
      #pragma unroll
      for (int ns = 0; ns < 2; ++ns) {
        const int n = wid * 32 + ns * 16 + li;
        bfr[ns] = *(const short8v*)((char*)Bs + ((n * 128 + kc * 64 + lg * 16) ^ ((n & 7) << 4)));
      }
      #pragma unroll
      for (int ms = 0; ms < 4; ++ms)
        #pragma unroll
        for (int ns = 0; ns < 2; ++ns)
          acc[ms][ns] = __builtin_amdgcn_mfma_f32_16x16x32_bf16(af[ms], bfr[ns], acc[ms][ns], 0, 0, 0);
    }
  }

  #pragma unroll
  for (int ms = 0; ms < 4; ++ms) {
    #pragma unroll
    for (int i = 0; i < 4; ++i) {
      float s = 0.f, sq = 0.f;
      #pragma unroll
      for (int ns = 0; ns < 2; ++ns) {
        const float b = b2[wid * 32 + ns * 16 + li];
        float v = fmaxf(acc[ms][ns][i] + b, 0.f);
        acc[ms][ns][i] = v;
        s += v; sq += v * v;
      }
      s += __shfl_xor(s, 1); sq += __shfl_xor(sq, 1);
      s += __shfl_xor(s, 2); sq += __shfl_xor(sq, 2);
      s += __shfl_xor(s, 4); sq += __shfl_xor(sq, 4);
      s += __shfl_xor(s, 8); sq += __shfl_xor(sq, 8);
      if (li == 0) {
        const int r = ms * 16 + lg * 4 + i;
        red[r][wid][0] = s; red[r][wid][1] = sq;
      }
    }
  }
  __syncthreads();

  const float g0 = g[wid * 32 + li],       g1 = g[wid * 32 + 16 + li];
  const float e0 = bb[wid * 32 + li],      e1 = bb[wid * 32 + 16 + li];
  #pragma unroll
  for (int ms = 0; ms < 4; ++ms) {
    #pragma unroll
    for (int i = 0; i < 4; ++i) {
      const int r = ms * 16 + lg * 4 + i;
      float s = 0.f, sq = 0.f;
      #pragma unroll
      for (int w = 0; w < 8; ++w) { s += red[r][w][0]; sq += red[r][w][1]; }
      const float mu = s * (1.f / 256.f);
      const float var = sq * (1.f / 256.f) - mu * mu;
      const float rs = rsqrtf(var + 1e-5f);
      float* zp = Z + (size_t)(n0 + r) * FDIM;
      zp[wid * 32 + li]      = (acc[ms][0][i] - mu) * rs * g0 + e0;
      zp[wid * 32 + 16 + li] = (acc[ms][1][i] - mu) * rs * g1 + e1;
    }
  }
}

// ---------------------------------------------------------------------------
// MFMA flash attention, SWAPPED QK^T (T12): sfT = mfma(K, Q) -> C[r][q].
// Column (q) reduction is 15 in-lane ops + 2 shfl; P repack via cvt_pk +
// vector LDS stores; PV computes Y^T = mfma(V^T, P^T) (Vl reads unchanged).
// ---------------------------------------------------------------------------
__global__ __launch_bounds__(256) void attn_mfma(
    const float* __restrict__ Qh, const float* __restrict__ Kh,
    const ushort* __restrict__ Vt, float* __restrict__ Pacc,
    float* __restrict__ Pml) {
  const int th = blockIdx.x, g = blockIdx.y;
  const int tid = threadIdx.x;
  const int wid = tid >> 6, lane = tid & 63;
  const int lg = lane >> 4, li = lane & 15;

  __shared__ ushort Kl[4096];   // [r 64][d 64] bf16, XOR-swizzled
  __shared__ ushort Vl[4096];   // V^T [d 64][r 64] bf16, XOR-swizzled
  __shared__ ushort Pl[8192];   // per-wave 4KB: P^T [q 32][r 64] bf16, swz

  // Q fragments (row=q=li, k=lg*8..): serve as B operand after swap.
  short8v qf[2][2];
  #pragma unroll
  for (int qsub = 0; qsub < 2; ++qsub)
    #pragma unroll
    for (int kc = 0; kc < 2; ++kc) {
      const float* qp = Qh + ((size_t)th * ANUM + wid * 32 + qsub * 16 + li) * DDIM + kc * 32 + lg * 8;
      float4 x = *(const float4*)qp;
      float4 y = *(const float4*)(qp + 4);
      qf[qsub][kc] = pack8(make_float4(x.x*0.5f, x.y*0.5f, x.z*0.5f, x.w*0.5f),
                           make_float4(y.x*0.5f, y.y*0.5f, y.z*0.5f, y.w*0.5f));
    }

  f32x4 yaccT[2][4];            // [qsub][dsub]: C row=d, col=q
  #pragma unroll
  for (int a = 0; a < 2; ++a)
    #pragma unroll
    for (int b = 0; b < 4; ++b)
      #pragma unroll
      for (int i = 0; i < 4; ++i) yaccT[a][b][i] = 0.f;

  float mq[2] = {-1e30f, -1e30f}, lq[2] = {0.f, 0.f};

  const float*  Kb = Kh + (size_t)th * RNUM * DDIM;
  const ushort* Vb = Vt + (size_t)th * 16 * 4096;

  const int krr = wid * 16 + (lane >> 2);
  const int kd0 = (lane & 3) * 16;

  for (int tt = 0; tt < 8; ++tt) {
    const int r0 = g * 512 + tt * 64;
    const int rt = g * 8 + tt;
    __syncthreads();
    {
      const float* kp = Kb + (size_t)(r0 + krr) * DDIM + kd0;
      float4 a = *(const float4*)kp,       b = *(const float4*)(kp + 4),
             c = *(const float4*)(kp + 8), d = *(const float4*)(kp + 12);
      const int base = krr * 128 + kd0 * 2;
      const int sw = (krr & 7) << 4;
      *(short8v*)((char*)Kl + (base ^ sw)) = pack8(a, b);
      *(short8v*)((char*)Kl + ((base + 16) ^ sw)) = pack8(c, d);
    }
    const ushort* vtile = Vb + rt * 4096;
    #pragma unroll
    for (int c = 0; c < 2; ++c) {
      const int B = (wid * 2 + c) * 1024 + lane * 16;
      const int sw = ((B >> 7) & 7) << 4;
      short8v v = *(const short8v*)((const char*)vtile + (B ^ sw));
      *(short8v*)((char*)Vl + B) = v;
    }
    __syncthreads();

    // ---- QK^T, swapped: sfT[qsub][rsub], C row=r (lg*4+i), col=q (li) ----
    f32x4 sfT[2][4];
    #pragma unroll
    for (int a = 0; a < 2; ++a)
      #pragma unroll
      for (int b = 0; b < 4; ++b)
        #pragma unroll
        for (int i = 0; i < 4; ++i) sfT[a][b][i] = 0.f;

    #pragma unroll
    for (int kc = 0; kc < 2; ++kc) {
      short8v kf[4];
      #pragma unroll
      for (int rsub = 0; rsub < 4; ++rsub) {
        const int rl = rsub * 16 + li;
        kf[rsub] = *(const short8v*)((char*)Kl + ((rl * 128 + kc * 64 + lg * 16) ^ ((rl & 7) << 4)));
      }
      #pragma unroll
      for (int qsub = 0; qsub < 2; ++qsub)
        #pragma unroll
        for (int rsub = 0; rsub < 4; ++rsub)
          sfT[qsub][rsub] = __builtin_amdgcn_mfma_f32_16x16x32_bf16(
              kf[rsub], qf[qsub][kc], sfT[qsub][rsub], 0, 0, 0);
    }

    // ---- online softmax per q-column (in-lane over 16 r + 2 shfl) ----
    #pragma unroll
    for (int qsub = 0; qsub < 2; ++qsub) {
      float em = sfT[qsub][0][0];
      #pragma unroll
      for (int rsub = 0; rsub < 4; ++rsub)
        #pragma unroll
        for (int i = 0; i < 4; ++i)
          em = fmaxf(em, sfT[qsub][rsub][i]);
      em = fmaxf(em, __shfl_xor(em, 16));
      em = fmaxf(em, __shfl_xor(em, 32));
      const float mn = fmaxf(mq[qsub], em);
      const float fs = __expf(mq[qsub] - mn);
      mq[qsub] = mn;
      float rs = 0.f;
      #pragma unroll
      for (int rsub = 0; rsub < 4; ++rsub)
        #pragma unroll
        for (int i = 0; i < 4; ++i) {
          const float p = __expf(sfT[qsub][rsub][i] - mn);
          sfT[qsub][rsub][i] = p;
          rs += p;
        }
      rs += __shfl_xor(rs, 16);
      rs += __shfl_xor(rs, 32);
      lq[qsub] = lq[qsub] * fs + rs;
      #pragma unroll
      for (int dsub = 0; dsub < 4; ++dsub)
        #pragma unroll
        for (int i = 0; i < 4; ++i) yaccT[qsub][dsub][i] *= fs;
      // pack P^T rows: q row = qloc, 4 consecutive r per rsub -> b64 store
      const int qloc = qsub * 16 + li;
      const int sw = (qloc & 7) << 4;
      char* pb = (char*)Pl + wid * 4096;
      #pragma unroll
      for (int rsub = 0; rsub < 4; ++rsub) {
        uint2 cc = {cvtpk(sfT[qsub][rsub][0], sfT[qsub][rsub][1]),
                    cvtpk(sfT[qsub][rsub][2], sfT[qsub][rsub][3])};
        *(uint2*)(pb + (qloc * 128 + ((rsub * 32 + lg * 8) ^ sw))) = cc;
      }
    }

    // ---- PV: Y^T = mfma(A=V^T frag, B=P^T frag) ----
    #pragma unroll
    for (int rc = 0; rc < 2; ++rc) {
      short8v pbf[2];
      #pragma unroll
      for (int qsub = 0; qsub < 2; ++qsub) {
        const int qloc = qsub * 16 + li;
        pbf[qsub] = *(const short8v*)((char*)Pl + wid * 4096 +
                     (qloc * 128 + ((rc * 64 + lg * 16) ^ ((qloc & 7) << 4))));
      }
      #pragma unroll
      for (int dsub = 0; dsub < 4; ++dsub) {
        const int dd = dsub * 16 + li;
        short8v vb = *(const short8v*)((char*)Vl +
                      ((dd * 128 + rc * 64 + lg * 16) ^ ((dd & 7) << 4)));
        #pragma unroll
        for (int qsub = 0; qsub < 2; ++qsub)
          yaccT[qsub][dsub] = __builtin_amdgcn_mfma_f32_16x16x32_bf16(
              vb, pbf[qsub], yaccT[qsub][dsub], 0, 0, 0);
      }
    }
  }

  // ---- outputs: Pacc[q][d] (float4), Pml for lg==0 lanes ----
  const int thg = th * 2 + g;
  float* pp = Pacc + (size_t)thg * 8192;
  #pragma unroll
  for (int qsub = 0; qsub < 2; ++qsub) {
    const int q = wid * 32 + qsub * 16 + li;
    #pragma unroll
    for (int dsub = 0; dsub < 4; ++dsub) {
      float4 o = {yaccT[qsub][dsub][0], yaccT[qsub][dsub][1],
                  yaccT[qsub][dsub][2], yaccT[qsub][dsub][3]};
      *(float4*)&pp[q * 64 + dsub * 16 + lg * 4] = o;
    }
    if (lg == 0) {
      Pml[(size_t)thg * 256 + q] = mq[qsub];
      Pml[(size_t)thg * 256 + 128 + q] = lq[qsub];
    }
  }
}

// ---------------------------------------------------------------------------
extern "C" void kernel_launch(void* const* d_in, const int* in_sizes, int n_in,
                              void* d_out, int out_size, void* d_ws, size_t ws_size,
                              hipStream_t stream) {
  (void)in_sizes; (void)n_in; (void)out_size; (void)ws_size;

  const float* agent   = (const float*)d_in[0];
  const float* rg      = (const float*)d_in[1];
  const float* W_K     = (const float*)d_in[2];
  const float* b_K     = (const float*)d_in[3];
  const float* W_V     = (const float*)d_in[4];
  const float* b_V     = (const float*)d_in[5];
  const float* W_Q     = (const float*)d_in[6];
  const float* b_Q     = (const float*)d_in[7];
  const float* q_scale = (const float*)d_in[8];
  const float* W_Y2    = (const float*)d_in[9];
  const float* b_Y2    = (const float*)d_in[10];
  const float* W_F1    = (const float*)d_in[11];
  const float* b_F1    = (const float*)d_in[12];
  const float* W_F2    = (const float*)d_in[13];
  const float* b_F2    = (const float*)d_in[14];
  const float* ln_g    = (const float*)d_in[15];
  const float* ln_b    = (const float*)d_in[16];

  float* out = (float*)d_out;
  float* Z  = out;                       // [A,T,F]
  float* Qh = out + 2981888;             // [T,H,A,D]
  float* Kh = out + 5963776;             // [T,H,R,D]
  float* Vh = out + 29818880;            // [T,H,R,D]

  // workspace (~86 MB):
  char* w = (char*)d_ws;
  ushort* WKt  = (ushort*)w;                    w += 65536 * 2;
  ushort* WVt  = (ushort*)w;                    w += 65536 * 2;
  ushort* WQt  = (ushort*)w;                    w += 65536 * 2;
  ushort* WY2t = (ushort*)w;                    w += 65536 * 2;
  ushort* WF1t = (ushort*)w;                    w += 262144 * 2;
  ushort* WF2t = (ushort*)w;                    w += 262144 * 2;
  float*  S    = (float*)w;                     w += (size_t)11648 * 256 * 4;
  float*  Pml  = (float*)w;                     w += (size_t)728 * 256 * 4;   // NOT aliased (y2 reads it while writing S)
  ushort* F1b  = (ushort*)w;                    w += (size_t)11648 * 1024 * 2;
  ushort* Vt   = (ushort*)w;                    // 23,855,104 ushort
  float*  Pacc = (float*)F1b;                   // 728*8192*4 B == F1b size; F1 written after Y2

  const dim3 blk(256);

  // all weight transposes in one launch
  wconv_all<<<dim3(3072), blk, 0, stream>>>(W_K, W_V, W_Q, W_Y2, W_F1, W_F2,
                                            WKt, WVt, WQt, WY2t, WF1t, WF2t);

  // fused K+V projection (rg read once)
  kvproj_fused<<<dim3(16, 91), dim3(512), 0, stream>>>(rg, WKt, WVt, b_K, b_V, Kh, Vh, Vt);
  // Q projection
  mfma_gemm<0><<<dim3(1, 182), blk, 0, stream>>>(agent, WQt, b_Q, Qh, q_scale);

  // attention partials (swapped-QK^T softmax)
  attn_mfma<<<dim3(364, 2), blk, 0, stream>>>(Qh, Kh, Vt, Pacc, Pml);

  // Y2 with fused combine -> S ; F1 -> bf16 ; F2+LN -> Z
  y2_gemm<<<dim3(182), blk, 0, stream>>>(Pacc, Pml, WY2t, b_Y2, S, agent);
  mfma_gemm<2><<<dim3(4, 182), blk, 0, stream>>>(S, WF1t, b_F1, (float*)F1b, nullptr);
  f2_ln_mfma<<<dim3(182), dim3(512), 0, stream>>>(F1b, WF2t, b_F2, ln_g, ln_b, Z);
}